// Round 3
// baseline (486.433 us; speedup 1.0000x reference)
//
#include <hip/hip_runtime.h>
#include <hip/hip_fp16.h>

// Problem constants
#define T_TOK 16384
#define HDIM  1024
#define NE    16
#define IDIM  128
#define BMq   64
#define NSLOT (T_TOK*2)                 // 32768 (every token in exactly 2 expert lists)
#define NSLOT_PAD (NSLOT + NE*BMq)      // 33792
#define NBLK1 (NSLOT_PAD/BMq)           // 528

typedef _Float16 half8 __attribute__((ext_vector_type(8)));
typedef _Float16 half4 __attribute__((ext_vector_type(4)));
typedef float    f32x4 __attribute__((ext_vector_type(4)));

// ---------------- workspace layout (bytes) ----------------
#define WS_TOKE 0              // int2[T]    131072
#define WS_TOKW 131072         // float2[T]  131072
#define WS_CNT  262144         // int[16]
#define WS_CUR  262208         // int[16]
#define WS_OFF  262272         // int[17]
#define WS_STOK 262400         // int[NSLOT_PAD]   135168
#define WS_SW   397568         // float[NSLOT_PAD] 135168
#define WS_ABUF 532736         // _Float16[NSLOT_PAD*128]  8650752  -> total ~9.2MB

// ---------------- router: logits, top2, softmax ----------------
__global__ __launch_bounds__(256) void router_k(const float* __restrict__ x,
                                                const float* __restrict__ Wr,
                                                int2* __restrict__ tok_e,
                                                float2* __restrict__ tok_w) {
    int wave = threadIdx.x >> 6;
    int lane = threadIdx.x & 63;
    int e = lane & 15, c = lane >> 4;          // lane computes expert e over h-chunk c
    int t0 = (blockIdx.x * 4 + wave) * 4;
    for (int ti = 0; ti < 4; ++ti) {
        int t = t0 + ti;
        const float4* xp = reinterpret_cast<const float4*>(x + (size_t)t * HDIM + c * 256);
        const float4* wp = reinterpret_cast<const float4*>(Wr + (size_t)e * HDIM + c * 256);
        float s = 0.f;
#pragma unroll 8
        for (int j = 0; j < 64; ++j) {
            float4 a = xp[j]; float4 b = wp[j];
            s += a.x * b.x + a.y * b.y + a.z * b.z + a.w * b.w;
        }
        s += __shfl_xor(s, 16);
        s += __shfl_xor(s, 32);                // lane holds logit for expert lane&15
        float v1 = -1e30f, v2 = -1e30f; int i1 = 0, i2 = 0;
#pragma unroll
        for (int q = 0; q < NE; ++q) {
            float lv = __shfl(s, q);           // logit of expert q
            if (lv > v1)      { v2 = v1; i2 = i1; v1 = lv; i1 = q; }
            else if (lv > v2) { v2 = lv; i2 = q; }
        }
        if (lane == 0) {
            float e2 = __expf(v2 - v1);
            float inv = 1.f / (1.f + e2);
            tok_e[t] = make_int2(i1, i2);
            tok_w[t] = make_float2(inv, e2 * inv);
        }
    }
}

// ---------------- per-expert token counts (no atomic contention) ----------------
__global__ __launch_bounds__(256) void count_k(const int2* __restrict__ tok_e,
                                               int* __restrict__ counts) {
    int e = blockIdx.x;                        // 16 blocks
    int c = 0;
    for (int t = threadIdx.x; t < T_TOK; t += 256) {
        int2 te = tok_e[t];
        c += (te.x == e) + (te.y == e);
    }
    __shared__ int red[256];
    red[threadIdx.x] = c; __syncthreads();
    for (int s = 128; s > 0; s >>= 1) {
        if (threadIdx.x < s) red[threadIdx.x] += red[threadIdx.x + s];
        __syncthreads();
    }
    if (threadIdx.x == 0) counts[e] = red[0];
}

// ---------------- padded exclusive scan ----------------
__global__ void scan_k(const int* __restrict__ counts, int* __restrict__ offs) {
    if (threadIdx.x == 0) {
        int acc = 0;
        for (int e = 0; e < NE; ++e) {
            offs[e] = acc;
            acc += ((counts[e] + BMq - 1) / BMq) * BMq;
        }
        offs[NE] = acc;
    }
}

// ---------------- scatter token->slot (block-aggregated atomics) ----------------
__global__ __launch_bounds__(256) void scatter_k(const int2* __restrict__ tok_e,
                                                 const float2* __restrict__ tok_w,
                                                 const int* __restrict__ offs,
                                                 int* __restrict__ cursors,
                                                 int* __restrict__ slot_tok,
                                                 float* __restrict__ slot_w) {
    __shared__ int lcnt[NE];
    __shared__ int lbase[NE];
    if (threadIdx.x < NE) lcnt[threadIdx.x] = 0;
    __syncthreads();
    int t = blockIdx.x * 256 + threadIdx.x;
    int2 te = tok_e[t]; float2 tw = tok_w[t];
    int p0 = atomicAdd(&lcnt[te.x], 1);
    int p1 = atomicAdd(&lcnt[te.y], 1);
    __syncthreads();
    if (threadIdx.x < NE)
        lbase[threadIdx.x] = atomicAdd(&cursors[threadIdx.x], lcnt[threadIdx.x]);
    __syncthreads();
    int s0 = offs[te.x] + lbase[te.x] + p0;
    int s1 = offs[te.y] + lbase[te.y] + p1;
    slot_tok[s0] = t; slot_w[s0] = tw.x;
    slot_tok[s1] = t; slot_w[s1] = tw.y;
}

// ---------------- GEMM1: a = silu(x_gathered @ Wg[e]^T + bg[e]) ----------------
// tile: 64 slots x 128 i, K=1024 in chunks of 64. 4 waves, wave w does i-strip [w*32,w*32+32)
__global__ __launch_bounds__(256) void gemm1_k(const float* __restrict__ x,
                                               const float* __restrict__ Wg,
                                               const float* __restrict__ bg,
                                               const int* __restrict__ offs,
                                               const int* __restrict__ slot_tok,
                                               _Float16* __restrict__ abuf) {
    __shared__ __align__(16) _Float16 As[64 * 64];    // [row][64] halves, XOR-swizzled
    __shared__ __align__(16) _Float16 Bs[128 * 64];   // [i][64]  halves, XOR-swizzled
    __shared__ int tokLds[64];
    int row0 = blockIdx.x * BMq;
    if (row0 >= offs[NE]) return;
    int e = 0;
#pragma unroll
    for (int q = 1; q < NE; ++q) if (offs[q] <= row0) e = q;
    int tid = threadIdx.x;
    if (tid < 64) tokLds[tid] = slot_tok[row0 + tid];
    __syncthreads();
    int wv = tid >> 6, lane = tid & 63;
    const float* Wge = Wg + (size_t)e * IDIM * HDIM;
    f32x4 acc[4][2] = {};
    for (int kk = 0; kk < HDIM; kk += 64) {
        // stage A: 64 rows x 16 float4 -> fp16 swizzled
#pragma unroll
        for (int j = 0; j < 4; ++j) {
            int idx = tid + j * 256;
            int r = idx >> 4, kq = idx & 15;
            int tok = tokLds[r];
            float4 v = make_float4(0.f, 0.f, 0.f, 0.f);
            if (tok >= 0) v = *reinterpret_cast<const float4*>(x + (size_t)tok * HDIM + kk + kq * 4);
            half4 hv = {(_Float16)v.x, (_Float16)v.y, (_Float16)v.z, (_Float16)v.w};
            *reinterpret_cast<half4*>(&As[r * 64 + ((kq * 4) ^ ((r & 7) << 3))]) = hv;
        }
        // stage B: Wg[e][i][kk..kk+63]: 128 rows x 16 float4
#pragma unroll 4
        for (int j = 0; j < 8; ++j) {
            int idx = tid + j * 256;
            int r = idx >> 4, kq = idx & 15;
            float4 v = *reinterpret_cast<const float4*>(Wge + (size_t)r * HDIM + kk + kq * 4);
            half4 hv = {(_Float16)v.x, (_Float16)v.y, (_Float16)v.z, (_Float16)v.w};
            *reinterpret_cast<half4*>(&Bs[r * 64 + ((kq * 4) ^ ((r & 7) << 3))]) = hv;
        }
        __syncthreads();
#pragma unroll
        for (int ks = 0; ks < 64; ks += 32) {
            int c = ks + ((lane >> 4) << 3);
            half8 af[4], bf[2];
#pragma unroll
            for (int rt = 0; rt < 4; ++rt) {
                int r = rt * 16 + (lane & 15);
                af[rt] = *reinterpret_cast<const half8*>(&As[r * 64 + (c ^ ((r & 7) << 3))]);
            }
#pragma unroll
            for (int ct = 0; ct < 2; ++ct) {
                int r = wv * 32 + ct * 16 + (lane & 15);
                bf[ct] = *reinterpret_cast<const half8*>(&Bs[r * 64 + (c ^ ((r & 7) << 3))]);
            }
#pragma unroll
            for (int rt = 0; rt < 4; ++rt)
#pragma unroll
                for (int ct = 0; ct < 2; ++ct)
                    acc[rt][ct] = __builtin_amdgcn_mfma_f32_16x16x32_f16(af[rt], bf[ct], acc[rt][ct], 0, 0, 0);
        }
        __syncthreads();
    }
    // epilogue: silu(acc + bg) -> abuf fp16
#pragma unroll
    for (int rt = 0; rt < 4; ++rt)
#pragma unroll
        for (int ct = 0; ct < 2; ++ct) {
            int i = wv * 32 + ct * 16 + (lane & 15);
            float bgv = bg[e * IDIM + i];
#pragma unroll
            for (int j = 0; j < 4; ++j) {
                int m = rt * 16 + ((lane >> 4) << 2) + j;
                if (tokLds[m] >= 0) {
                    float v = acc[rt][ct][j] + bgv;
                    float sv = v / (1.f + __expf(-v));
                    abuf[(size_t)(row0 + m) * IDIM + i] = (_Float16)sv;
                }
            }
        }
}

// ---------------- GEMM2: out[tok] += w * (a @ Wu[e]^T + bu[e]) ----------------
// tile: 64 slots x 128 h, K=128. grid (NBLK1, 8)
__global__ __launch_bounds__(256) void gemm2_k(const _Float16* __restrict__ abuf,
                                               const float* __restrict__ Wu,
                                               const float* __restrict__ bu,
                                               const int* __restrict__ offs,
                                               const int* __restrict__ slot_tok,
                                               const float* __restrict__ slot_w,
                                               float* __restrict__ out) {
    __shared__ __align__(16) _Float16 As[64 * 128];    // 16KB
    __shared__ __align__(16) _Float16 Bs[128 * 128];   // 32KB
    __shared__ int   tokLds[64];
    __shared__ float wLds[64];
    int row0 = blockIdx.x * BMq;
    if (row0 >= offs[NE]) return;
    int h0 = blockIdx.y * 128;
    int e = 0;
#pragma unroll
    for (int q = 1; q < NE; ++q) if (offs[q] <= row0) e = q;
    int tid = threadIdx.x;
    if (tid < 64) { tokLds[tid] = slot_tok[row0 + tid]; wLds[tid] = slot_w[row0 + tid]; }
    // stage A: abuf rows (fp16, no conversion): 64 rows x 32 half4  (2048 half4 total)
#pragma unroll
    for (int j = 0; j < 8; ++j) {
        int idx = tid + j * 256;
        int r = idx >> 5, hq = idx & 31;
        half4 v = *reinterpret_cast<const half4*>(abuf + (size_t)(row0 + r) * IDIM + hq * 4);
        *reinterpret_cast<half4*>(&As[r * 128 + ((hq * 4) ^ ((r & 7) << 3))]) = v;
    }
    // stage B: Wu[e][h0+r][i] fp32 -> fp16: 128 rows x 32 float4
    const float* Wue = Wu + (size_t)e * HDIM * IDIM;
#pragma unroll 4
    for (int j = 0; j < 16; ++j) {
        int idx = tid + j * 256;
        int r = idx >> 5, fq = idx & 31;
        float4 v = *reinterpret_cast<const float4*>(Wue + (size_t)(h0 + r) * IDIM + fq * 4);
        half4 hv = {(_Float16)v.x, (_Float16)v.y, (_Float16)v.z, (_Float16)v.w};
        *reinterpret_cast<half4*>(&Bs[r * 128 + ((fq * 4) ^ ((r & 7) << 3))]) = hv;
    }
    __syncthreads();
    int wv = tid >> 6, lane = tid & 63;
    f32x4 acc[4][2] = {};
#pragma unroll
    for (int ks = 0; ks < 128; ks += 32) {
        int c = ks + ((lane >> 4) << 3);
        half8 af[4], bf[2];
#pragma unroll
        for (int rt = 0; rt < 4; ++rt) {
            int r = rt * 16 + (lane & 15);
            af[rt] = *reinterpret_cast<const half8*>(&As[r * 128 + (c ^ ((r & 7) << 3))]);
        }
#pragma unroll
        for (int ct = 0; ct < 2; ++ct) {
            int r = wv * 32 + ct * 16 + (lane & 15);
            bf[ct] = *reinterpret_cast<const half8*>(&Bs[r * 128 + (c ^ ((r & 7) << 3))]);
        }
#pragma unroll
        for (int rt = 0; rt < 4; ++rt)
#pragma unroll
            for (int ct = 0; ct < 2; ++ct)
                acc[rt][ct] = __builtin_amdgcn_mfma_f32_16x16x32_f16(af[rt], bf[ct], acc[rt][ct], 0, 0, 0);
    }
    // epilogue: weighted scatter-add
#pragma unroll
    for (int rt = 0; rt < 4; ++rt)
#pragma unroll
        for (int ct = 0; ct < 2; ++ct) {
            int h = h0 + wv * 32 + ct * 16 + (lane & 15);
            float buv = bu[e * HDIM + h];
#pragma unroll
            for (int j = 0; j < 4; ++j) {
                int m = rt * 16 + ((lane >> 4) << 2) + j;
                int tok = tokLds[m];
                if (tok >= 0)
                    atomicAdd(out + (size_t)tok * HDIM + h, (acc[rt][ct][j] + buv) * wLds[m]);
            }
        }
}

extern "C" void kernel_launch(void* const* d_in, const int* in_sizes, int n_in,
                              void* d_out, int out_size, void* d_ws, size_t ws_size,
                              hipStream_t stream) {
    const float* x  = (const float*)d_in[0];
    const float* Wr = (const float*)d_in[1];
    const float* Wg = (const float*)d_in[2];
    const float* bg = (const float*)d_in[3];
    const float* Wu = (const float*)d_in[4];
    const float* bu = (const float*)d_in[5];
    float* out = (float*)d_out;
    char* ws = (char*)d_ws;

    int2*      tok_e    = (int2*)(ws + WS_TOKE);
    float2*    tok_w    = (float2*)(ws + WS_TOKW);
    int*       counts   = (int*)(ws + WS_CNT);
    int*       cursors  = (int*)(ws + WS_CUR);
    int*       offs     = (int*)(ws + WS_OFF);
    int*       slot_tok = (int*)(ws + WS_STOK);
    float*     slot_w   = (float*)(ws + WS_SW);
    _Float16*  abuf     = (_Float16*)(ws + WS_ABUF);

    hipMemsetAsync(ws + WS_CNT, 0, 256, stream);                       // counts+cursors+offs
    hipMemsetAsync(slot_tok, 0xFF, NSLOT_PAD * sizeof(int), stream);   // -1 = inactive slot
    hipMemsetAsync(d_out, 0, (size_t)T_TOK * HDIM * sizeof(float), stream);

    router_k <<<T_TOK / 16, 256, 0, stream>>>(x, Wr, tok_e, tok_w);
    count_k  <<<NE, 256, 0, stream>>>(tok_e, counts);
    scan_k   <<<1, 64, 0, stream>>>(counts, offs);
    scatter_k<<<T_TOK / 256, 256, 0, stream>>>(tok_e, tok_w, offs, cursors, slot_tok, slot_w);
    gemm1_k  <<<NBLK1, 256, 0, stream>>>(x, Wg, bg, offs, slot_tok, abuf);
    dim3 g2(NBLK1, 8);
    gemm2_k  <<<g2, 256, 0, stream>>>(abuf, Wu, bu, offs, slot_tok, slot_w, out);
}

// Round 4
// 285.272 us; speedup vs baseline: 1.7052x; 1.7052x over previous
//
#include <hip/hip_runtime.h>
#include <hip/hip_fp16.h>

// Problem constants
#define T_TOK 16384
#define HDIM  1024
#define NE    16
#define IDIM  128
#define BMq   64
#define NSLOT (T_TOK*2)                 // 32768
#define NSLOT_PAD (NSLOT + NE*BMq)      // 33792
#define NBLK1 (NSLOT_PAD/BMq)           // 528

typedef _Float16 half8 __attribute__((ext_vector_type(8)));
typedef _Float16 half4 __attribute__((ext_vector_type(4)));
typedef float    f32x4 __attribute__((ext_vector_type(4)));

// ---------------- workspace layout (bytes) ----------------
// BASE region (identical to the passing round-3 layout):
#define WS_TOKE 0              // int2[T]    131072
#define WS_TOKW 131072         // float2[T]  131072
#define WS_CNT  262144         // int[16]
#define WS_CUR  262208         // int[16]
#define WS_OFF  262272         // int[17]
#define WS_STOK 262400         // int[NSLOT_PAD]   135168
#define WS_SW   397568         // float[NSLOT_PAD] 135168
#define WS_ABUF 532736         // _Float16[NSLOT_PAD*128]  8650752 -> 9183488
// FULL-tier extras (only touched when ws_size >= WS_FULL_END):
#define WS_TSLOT 9183488ULL    // int2[T]                 131072 -> 9314560
#define WS_WG16  9314560ULL    // half[16*128*1024]      4194304 -> 13508864
#define WS_WU16  13508864ULL   // half[16*1024*128]      4194304 -> 17703168
#define WS_X16   17703168ULL   // half[T*1024]          33554432 -> 51257600
#define WS_OBUF  51257600ULL   // half[NSLOT_PAD*1024]  69206016 -> 120463616
#define WS_FULL_END 120463616ULL

// ---------------- router: MFMA logits (fp16 hi/lo = fp32-accurate), top2, softmax ----
// 1 wave per 16-token tile. logit = xh*wh + (xh*wl_s + xl_s*wh)/2048, lo terms
// pre-scaled by 2^11 so they stay in fp16 normal range (no denorm-flush risk).
template<bool WX>
__global__ __launch_bounds__(64) void router_k(const float* __restrict__ x,
                                               const float* __restrict__ Wr,
                                               int2* __restrict__ tok_e,
                                               float2* __restrict__ tok_w,
                                               _Float16* __restrict__ x16) {
    __shared__ __align__(16) _Float16 Ah[16*64], Al[16*64], Bh[16*64], Bl[16*64];
    int lane = threadIdx.x;
    int tile0 = blockIdx.x * 16;
    f32x4 accM = {0.f,0.f,0.f,0.f};
    f32x4 accC = {0.f,0.f,0.f,0.f};
    for (int kk = 0; kk < HDIM; kk += 64) {
        __syncthreads();
#pragma unroll
        for (int s = 0; s < 4; ++s) {
            int idx = lane + s*64;
            int r = idx >> 4, kq = idx & 15;       // r: token-row / expert-row, kq: float4 in k
            float4 xv = *reinterpret_cast<const float4*>(x  + (size_t)(tile0 + r)*HDIM + kk + kq*4);
            float4 wv = *reinterpret_cast<const float4*>(Wr + (size_t)r*HDIM + kk + kq*4);
            half4 xh, xl, wh, wl;
            {
                float v0=xv.x,v1=xv.y,v2=xv.z,v3=xv.w;
                xh[0]=(_Float16)v0; xh[1]=(_Float16)v1; xh[2]=(_Float16)v2; xh[3]=(_Float16)v3;
                xl[0]=(_Float16)((v0-(float)xh[0])*2048.f); xl[1]=(_Float16)((v1-(float)xh[1])*2048.f);
                xl[2]=(_Float16)((v2-(float)xh[2])*2048.f); xl[3]=(_Float16)((v3-(float)xh[3])*2048.f);
                float w0=wv.x,w1=wv.y,w2=wv.z,w3=wv.w;
                wh[0]=(_Float16)w0; wh[1]=(_Float16)w1; wh[2]=(_Float16)w2; wh[3]=(_Float16)w3;
                wl[0]=(_Float16)((w0-(float)wh[0])*2048.f); wl[1]=(_Float16)((w1-(float)wh[1])*2048.f);
                wl[2]=(_Float16)((w2-(float)wh[2])*2048.f); wl[3]=(_Float16)((w3-(float)wh[3])*2048.f);
            }
            int sw = (kq*4) ^ ((r & 7) << 3);
            *reinterpret_cast<half4*>(&Ah[r*64 + sw]) = xh;
            *reinterpret_cast<half4*>(&Al[r*64 + sw]) = xl;
            *reinterpret_cast<half4*>(&Bh[r*64 + sw]) = wh;
            *reinterpret_cast<half4*>(&Bl[r*64 + sw]) = wl;
            if (WX)
                *reinterpret_cast<half4*>(x16 + (size_t)(tile0 + r)*HDIM + kk + kq*4) = xh;
        }
        __syncthreads();
        int rr = lane & 15;
        int swr = (rr & 7) << 3;
#pragma unroll
        for (int ks = 0; ks < 64; ks += 32) {
            int c = ks + ((lane >> 4) << 3);
            half8 axh = *reinterpret_cast<const half8*>(&Ah[rr*64 + (c ^ swr)]);
            half8 axl = *reinterpret_cast<const half8*>(&Al[rr*64 + (c ^ swr)]);
            half8 bwh = *reinterpret_cast<const half8*>(&Bh[rr*64 + (c ^ swr)]);
            half8 bwl = *reinterpret_cast<const half8*>(&Bl[rr*64 + (c ^ swr)]);
            accM = __builtin_amdgcn_mfma_f32_16x16x32_f16(axh, bwh, accM, 0, 0, 0);
            accC = __builtin_amdgcn_mfma_f32_16x16x32_f16(axh, bwl, accC, 0, 0, 0);
            accC = __builtin_amdgcn_mfma_f32_16x16x32_f16(axl, bwh, accC, 0, 0, 0);
        }
    }
    // C layout: token = (lane>>4)*4 + j, expert = lane&15 (HW-verified mapping)
    int c = lane & 15, g = lane >> 4;
#pragma unroll
    for (int j = 0; j < 4; ++j) {
        float v1 = accM[j] + accC[j] * (1.f/2048.f);
        int   i1 = c;
        float v2 = -1e30f; int i2 = 16;
#pragma unroll
        for (int m = 1; m < 16; m <<= 1) {          // butterfly top-2 merge over 16 lanes
            float ov1 = __shfl_xor(v1, m); int oi1 = __shfl_xor(i1, m);
            float ov2 = __shfl_xor(v2, m); int oi2 = __shfl_xor(i2, m);
            float nv1, nv2; int ni1, ni2;
            bool aFirst = (v1 > ov1) || (v1 == ov1 && i1 < oi1);
            if (aFirst) {
                nv1 = v1; ni1 = i1;
                if ((v2 > ov1) || (v2 == ov1 && i2 < oi1)) { nv2 = v2; ni2 = i2; }
                else                                        { nv2 = ov1; ni2 = oi1; }
            } else {
                nv1 = ov1; ni1 = oi1;
                if ((ov2 > v1) || (ov2 == v1 && oi2 < i1)) { nv2 = ov2; ni2 = oi2; }
                else                                        { nv2 = v1; ni2 = i1; }
            }
            v1 = nv1; i1 = ni1; v2 = nv2; i2 = ni2;
        }
        if (c == 0) {
            int t = tile0 + g*4 + j;
            float e2 = __expf(v2 - v1);
            float inv = 1.f / (1.f + e2);
            tok_e[t] = make_int2(i1, i2);
            tok_w[t] = make_float2(inv, e2 * inv);
        }
    }
}

// ---------------- weight fp32->fp16 pre-convert (FULL tier) ----------------
__global__ __launch_bounds__(256) void cvtw_k(const float* __restrict__ Wg,
                                              const float* __restrict__ Wu,
                                              _Float16* __restrict__ Wg16,
                                              _Float16* __restrict__ Wu16) {
    int i = blockIdx.x * 256 + threadIdx.x;        // 524288 float4 per array
    float4 g = reinterpret_cast<const float4*>(Wg)[i];
    float4 u = reinterpret_cast<const float4*>(Wu)[i];
    half4 gh = {(_Float16)g.x,(_Float16)g.y,(_Float16)g.z,(_Float16)g.w};
    half4 uh = {(_Float16)u.x,(_Float16)u.y,(_Float16)u.z,(_Float16)u.w};
    reinterpret_cast<half4*>(Wg16)[i] = gh;
    reinterpret_cast<half4*>(Wu16)[i] = uh;
}

// ---------------- per-expert token counts ----------------
__global__ __launch_bounds__(256) void count_k(const int2* __restrict__ tok_e,
                                               int* __restrict__ counts) {
    int e = blockIdx.x;
    int c = 0;
    for (int t = threadIdx.x; t < T_TOK; t += 256) {
        int2 te = tok_e[t];
        c += (te.x == e) + (te.y == e);
    }
    __shared__ int red[256];
    red[threadIdx.x] = c; __syncthreads();
    for (int s = 128; s > 0; s >>= 1) {
        if (threadIdx.x < s) red[threadIdx.x] += red[threadIdx.x + s];
        __syncthreads();
    }
    if (threadIdx.x == 0) counts[e] = red[0];
}

// ---------------- padded exclusive scan ----------------
__global__ void scan_k(const int* __restrict__ counts, int* __restrict__ offs) {
    if (threadIdx.x == 0) {
        int acc = 0;
        for (int e = 0; e < NE; ++e) {
            offs[e] = acc;
            acc += ((counts[e] + BMq - 1) / BMq) * BMq;
        }
        offs[NE] = acc;
    }
}

// ---------------- scatter token->slot ----------------
template<bool FULL>
__global__ __launch_bounds__(256) void scatter_k(const int2* __restrict__ tok_e,
                                                 const float2* __restrict__ tok_w,
                                                 const int* __restrict__ offs,
                                                 int* __restrict__ cursors,
                                                 int* __restrict__ slot_tok,
                                                 float* __restrict__ slot_w,
                                                 int2* __restrict__ tok_slots) {
    __shared__ int lcnt[NE];
    __shared__ int lbase[NE];
    if (threadIdx.x < NE) lcnt[threadIdx.x] = 0;
    __syncthreads();
    int t = blockIdx.x * 256 + threadIdx.x;
    int2 te = tok_e[t]; float2 tw = tok_w[t];
    int p0 = atomicAdd(&lcnt[te.x], 1);
    int p1 = atomicAdd(&lcnt[te.y], 1);
    __syncthreads();
    if (threadIdx.x < NE)
        lbase[threadIdx.x] = atomicAdd(&cursors[threadIdx.x], lcnt[threadIdx.x]);
    __syncthreads();
    int s0 = offs[te.x] + lbase[te.x] + p0;
    int s1 = offs[te.y] + lbase[te.y] + p1;
    slot_tok[s0] = t; slot_w[s0] = tw.x;
    slot_tok[s1] = t; slot_w[s1] = tw.y;
    if (FULL) tok_slots[t] = make_int2(s0, s1);
}

// ---------------- GEMM1: a = silu(x_gathered @ Wg[e]^T + bg[e]) ----------------
template<bool FULL>
__global__ __launch_bounds__(256) void gemm1_k(const float* __restrict__ x,
                                               const _Float16* __restrict__ x16,
                                               const float* __restrict__ Wg,
                                               const _Float16* __restrict__ Wg16,
                                               const float* __restrict__ bg,
                                               const int* __restrict__ offs,
                                               const int* __restrict__ slot_tok,
                                               _Float16* __restrict__ abuf) {
    __shared__ __align__(16) _Float16 As[64 * 64];
    __shared__ __align__(16) _Float16 Bs[128 * 64];
    __shared__ int tokLds[64];
    int row0 = blockIdx.x * BMq;
    if (row0 >= offs[NE]) return;
    int e = 0;
#pragma unroll
    for (int q = 1; q < NE; ++q) if (offs[q] <= row0) e = q;
    int tid = threadIdx.x;
    if (tid < 64) tokLds[tid] = slot_tok[row0 + tid];
    __syncthreads();
    int wv = tid >> 6, lane = tid & 63;
    f32x4 acc[4][2] = {};
    for (int kk = 0; kk < HDIM; kk += 64) {
        if (FULL) {
            // A: 64 rows x 8 half8 gathered from x16
#pragma unroll
            for (int j = 0; j < 2; ++j) {
                int idx = tid + j * 256;
                int r = idx >> 3, hq = idx & 7;
                int tok = tokLds[r];
                half8 v = {0,0,0,0,0,0,0,0};
                if (tok >= 0) v = *reinterpret_cast<const half8*>(x16 + (size_t)tok * HDIM + kk + hq * 8);
                *reinterpret_cast<half8*>(&As[r * 64 + ((hq * 8) ^ ((r & 7) << 3))]) = v;
            }
            // B: Wg16[e]: 128 rows x 8 half8
#pragma unroll
            for (int j = 0; j < 4; ++j) {
                int idx = tid + j * 256;
                int r = idx >> 3, hq = idx & 7;
                half8 v = *reinterpret_cast<const half8*>(Wg16 + (size_t)e * IDIM * HDIM + (size_t)r * HDIM + kk + hq * 8);
                *reinterpret_cast<half8*>(&Bs[r * 64 + ((hq * 8) ^ ((r & 7) << 3))]) = v;
            }
        } else {
#pragma unroll
            for (int j = 0; j < 4; ++j) {
                int idx = tid + j * 256;
                int r = idx >> 4, kq = idx & 15;
                int tok = tokLds[r];
                float4 v = make_float4(0.f, 0.f, 0.f, 0.f);
                if (tok >= 0) v = *reinterpret_cast<const float4*>(x + (size_t)tok * HDIM + kk + kq * 4);
                half4 hv = {(_Float16)v.x, (_Float16)v.y, (_Float16)v.z, (_Float16)v.w};
                *reinterpret_cast<half4*>(&As[r * 64 + ((kq * 4) ^ ((r & 7) << 3))]) = hv;
            }
#pragma unroll 4
            for (int j = 0; j < 8; ++j) {
                int idx = tid + j * 256;
                int r = idx >> 4, kq = idx & 15;
                float4 v = *reinterpret_cast<const float4*>(Wg + (size_t)e * IDIM * HDIM + (size_t)r * HDIM + kk + kq * 4);
                half4 hv = {(_Float16)v.x, (_Float16)v.y, (_Float16)v.z, (_Float16)v.w};
                *reinterpret_cast<half4*>(&Bs[r * 64 + ((kq * 4) ^ ((r & 7) << 3))]) = hv;
            }
        }
        __syncthreads();
#pragma unroll
        for (int ks = 0; ks < 64; ks += 32) {
            int c = ks + ((lane >> 4) << 3);
            half8 af[4], bf[2];
#pragma unroll
            for (int rt = 0; rt < 4; ++rt) {
                int r = rt * 16 + (lane & 15);
                af[rt] = *reinterpret_cast<const half8*>(&As[r * 64 + (c ^ ((r & 7) << 3))]);
            }
#pragma unroll
            for (int ct = 0; ct < 2; ++ct) {
                int r = wv * 32 + ct * 16 + (lane & 15);
                bf[ct] = *reinterpret_cast<const half8*>(&Bs[r * 64 + (c ^ ((r & 7) << 3))]);
            }
#pragma unroll
            for (int rt = 0; rt < 4; ++rt)
#pragma unroll
                for (int ct = 0; ct < 2; ++ct)
                    acc[rt][ct] = __builtin_amdgcn_mfma_f32_16x16x32_f16(af[rt], bf[ct], acc[rt][ct], 0, 0, 0);
        }
        __syncthreads();
    }
#pragma unroll
    for (int rt = 0; rt < 4; ++rt)
#pragma unroll
        for (int ct = 0; ct < 2; ++ct) {
            int i = wv * 32 + ct * 16 + (lane & 15);
            float bgv = bg[e * IDIM + i];
#pragma unroll
            for (int j = 0; j < 4; ++j) {
                int m = rt * 16 + ((lane >> 4) << 2) + j;
                if (tokLds[m] >= 0) {
                    float v = acc[rt][ct][j] + bgv;
                    float sv = v / (1.f + __expf(-v));
                    abuf[(size_t)(row0 + m) * IDIM + i] = (_Float16)sv;
                }
            }
        }
}

// ---------------- GEMM2: O_slot = a @ Wu[e]^T  (FULL: store; BASE: atomic) ----
template<bool FULL>
__global__ __launch_bounds__(256) void gemm2_k(const _Float16* __restrict__ abuf,
                                               const float* __restrict__ Wu,
                                               const _Float16* __restrict__ Wu16,
                                               const float* __restrict__ bu,
                                               const int* __restrict__ offs,
                                               const int* __restrict__ slot_tok,
                                               const float* __restrict__ slot_w,
                                               float* __restrict__ out,
                                               _Float16* __restrict__ Obuf) {
    __shared__ __align__(16) _Float16 As[64 * 128];
    __shared__ __align__(16) _Float16 Bs[128 * 128];
    __shared__ int   tokLds[64];
    __shared__ float wLds[64];
    int row0 = blockIdx.x * BMq;
    if (row0 >= offs[NE]) return;
    int h0 = blockIdx.y * 128;
    int e = 0;
#pragma unroll
    for (int q = 1; q < NE; ++q) if (offs[q] <= row0) e = q;
    int tid = threadIdx.x;
    if (tid < 64) { tokLds[tid] = slot_tok[row0 + tid]; wLds[tid] = slot_w[row0 + tid]; }
    // A: abuf rows, 64 x 16 half8
#pragma unroll
    for (int j = 0; j < 4; ++j) {
        int idx = tid + j * 256;
        int r = idx >> 4, hq = idx & 15;
        half8 v = *reinterpret_cast<const half8*>(abuf + (size_t)(row0 + r) * IDIM + hq * 8);
        *reinterpret_cast<half8*>(&As[r * 128 + ((hq * 8) ^ ((r & 7) << 3))]) = v;
    }
    if (FULL) {
#pragma unroll
        for (int j = 0; j < 8; ++j) {
            int idx = tid + j * 256;
            int r = idx >> 4, fq = idx & 15;
            half8 v = *reinterpret_cast<const half8*>(Wu16 + (size_t)e * HDIM * IDIM + (size_t)(h0 + r) * IDIM + fq * 8);
            *reinterpret_cast<half8*>(&Bs[r * 128 + ((fq * 8) ^ ((r & 7) << 3))]) = v;
        }
    } else {
#pragma unroll 4
        for (int j = 0; j < 16; ++j) {
            int idx = tid + j * 256;
            int r = idx >> 5, fq = idx & 31;
            float4 v = *reinterpret_cast<const float4*>(Wu + (size_t)e * HDIM * IDIM + (size_t)(h0 + r) * IDIM + fq * 4);
            half4 hv = {(_Float16)v.x, (_Float16)v.y, (_Float16)v.z, (_Float16)v.w};
            *reinterpret_cast<half4*>(&Bs[r * 128 + ((fq * 4) ^ ((r & 7) << 3))]) = hv;
        }
    }
    __syncthreads();
    int wv = tid >> 6, lane = tid & 63;
    f32x4 acc[4][2] = {};
#pragma unroll
    for (int ks = 0; ks < 128; ks += 32) {
        int c = ks + ((lane >> 4) << 3);
        half8 af[4], bf[2];
#pragma unroll
        for (int rt = 0; rt < 4; ++rt) {
            int r = rt * 16 + (lane & 15);
            af[rt] = *reinterpret_cast<const half8*>(&As[r * 128 + (c ^ ((r & 7) << 3))]);
        }
#pragma unroll
        for (int ct = 0; ct < 2; ++ct) {
            int r = wv * 32 + ct * 16 + (lane & 15);
            bf[ct] = *reinterpret_cast<const half8*>(&Bs[r * 128 + (c ^ ((r & 7) << 3))]);
        }
#pragma unroll
        for (int rt = 0; rt < 4; ++rt)
#pragma unroll
            for (int ct = 0; ct < 2; ++ct)
                acc[rt][ct] = __builtin_amdgcn_mfma_f32_16x16x32_f16(af[rt], bf[ct], acc[rt][ct], 0, 0, 0);
    }
#pragma unroll
    for (int rt = 0; rt < 4; ++rt)
#pragma unroll
        for (int ct = 0; ct < 2; ++ct) {
            int h = h0 + wv * 32 + ct * 16 + (lane & 15);
#pragma unroll
            for (int j = 0; j < 4; ++j) {
                int m = rt * 16 + ((lane >> 4) << 2) + j;
                if (FULL) {
                    Obuf[(size_t)(row0 + m) * HDIM + h] = (_Float16)acc[rt][ct][j];
                } else {
                    int tok = tokLds[m];
                    if (tok >= 0)
                        atomicAdd(out + (size_t)tok * HDIM + h,
                                  (acc[rt][ct][j] + bu[e * HDIM + h]) * wLds[m]);
                }
            }
        }
}

// ---------------- combine (FULL): out[t] = w1*(O1+bu[e1]) + w2*(O2+bu[e2]) ----
__global__ __launch_bounds__(256) void combine_k(const _Float16* __restrict__ Obuf,
                                                 const float* __restrict__ bu,
                                                 const int2* __restrict__ tok_slots,
                                                 const int2* __restrict__ tok_e,
                                                 const float2* __restrict__ tok_w,
                                                 float* __restrict__ out) {
    int wv = threadIdx.x >> 6, lane = threadIdx.x & 63;
    int t = blockIdx.x * 4 + wv;
    int2   sl = tok_slots[t];
    int2   te = tok_e[t];
    float2 tw = tok_w[t];
    const _Float16* O1 = Obuf + (size_t)sl.x * HDIM;
    const _Float16* O2 = Obuf + (size_t)sl.y * HDIM;
    const float* b1 = bu + (size_t)te.x * HDIM;
    const float* b2 = bu + (size_t)te.y * HDIM;
    float* op = out + (size_t)t * HDIM;
#pragma unroll
    for (int q = 0; q < 4; ++q) {
        int h = q * 256 + lane * 4;
        half4  a1 = *reinterpret_cast<const half4*>(O1 + h);
        half4  a2 = *reinterpret_cast<const half4*>(O2 + h);
        float4 v1 = *reinterpret_cast<const float4*>(b1 + h);
        float4 v2 = *reinterpret_cast<const float4*>(b2 + h);
        float4 o;
        o.x = tw.x * ((float)a1[0] + v1.x) + tw.y * ((float)a2[0] + v2.x);
        o.y = tw.x * ((float)a1[1] + v1.y) + tw.y * ((float)a2[1] + v2.y);
        o.z = tw.x * ((float)a1[2] + v1.z) + tw.y * ((float)a2[2] + v2.z);
        o.w = tw.x * ((float)a1[3] + v1.w) + tw.y * ((float)a2[3] + v2.w);
        *reinterpret_cast<float4*>(op + h) = o;
    }
}

extern "C" void kernel_launch(void* const* d_in, const int* in_sizes, int n_in,
                              void* d_out, int out_size, void* d_ws, size_t ws_size,
                              hipStream_t stream) {
    const float* x  = (const float*)d_in[0];
    const float* Wr = (const float*)d_in[1];
    const float* Wg = (const float*)d_in[2];
    const float* bg = (const float*)d_in[3];
    const float* Wu = (const float*)d_in[4];
    const float* bu = (const float*)d_in[5];
    float* out = (float*)d_out;
    char* ws = (char*)d_ws;

    int2*      tok_e    = (int2*)(ws + WS_TOKE);
    float2*    tok_w    = (float2*)(ws + WS_TOKW);
    int*       counts   = (int*)(ws + WS_CNT);
    int*       cursors  = (int*)(ws + WS_CUR);
    int*       offs     = (int*)(ws + WS_OFF);
    int*       slot_tok = (int*)(ws + WS_STOK);
    float*     slot_w   = (float*)(ws + WS_SW);
    _Float16*  abuf     = (_Float16*)(ws + WS_ABUF);
    int2*      tok_slots= (int2*)(ws + WS_TSLOT);
    _Float16*  Wg16     = (_Float16*)(ws + WS_WG16);
    _Float16*  Wu16     = (_Float16*)(ws + WS_WU16);
    _Float16*  x16      = (_Float16*)(ws + WS_X16);
    _Float16*  Obuf     = (_Float16*)(ws + WS_OBUF);

    const bool full = (ws_size >= WS_FULL_END);   // constant per process -> capture-safe

    hipMemsetAsync(ws + WS_CNT, 0, 256, stream);
    hipMemsetAsync(slot_tok, 0xFF, NSLOT_PAD * sizeof(int), stream);

    if (full) {
        cvtw_k   <<<2048, 256, 0, stream>>>(Wg, Wu, Wg16, Wu16);
        router_k<true><<<T_TOK/16, 64, 0, stream>>>(x, Wr, tok_e, tok_w, x16);
        count_k  <<<NE, 256, 0, stream>>>(tok_e, counts);
        scan_k   <<<1, 64, 0, stream>>>(counts, offs);
        scatter_k<true><<<T_TOK/256, 256, 0, stream>>>(tok_e, tok_w, offs, cursors, slot_tok, slot_w, tok_slots);
        gemm1_k<true><<<NBLK1, 256, 0, stream>>>(x, x16, Wg, Wg16, bg, offs, slot_tok, abuf);
        dim3 g2(NBLK1, 8);
        gemm2_k<true><<<g2, 256, 0, stream>>>(abuf, Wu, Wu16, bu, offs, slot_tok, slot_w, out, Obuf);
        combine_k<<<T_TOK/4, 256, 0, stream>>>(Obuf, bu, tok_slots, tok_e, tok_w, out);
    } else {
        hipMemsetAsync(d_out, 0, (size_t)T_TOK * HDIM * sizeof(float), stream);
        router_k<false><<<T_TOK/16, 64, 0, stream>>>(x, Wr, tok_e, tok_w, nullptr);
        count_k  <<<NE, 256, 0, stream>>>(tok_e, counts);
        scan_k   <<<1, 64, 0, stream>>>(counts, offs);
        scatter_k<false><<<T_TOK/256, 256, 0, stream>>>(tok_e, tok_w, offs, cursors, slot_tok, slot_w, nullptr);
        gemm1_k<false><<<NBLK1, 256, 0, stream>>>(x, nullptr, Wg, nullptr, bg, offs, slot_tok, abuf);
        dim3 g2(NBLK1, 8);
        gemm2_k<false><<<g2, 256, 0, stream>>>(abuf, Wu, nullptr, bu, offs, slot_tok, slot_w, out, nullptr);
    }
}

// Round 5
// 274.756 us; speedup vs baseline: 1.7704x; 1.0383x over previous
//
#include <hip/hip_runtime.h>
#include <hip/hip_fp16.h>

// Problem constants
#define T_TOK 16384
#define HDIM  1024
#define NE    16
#define IDIM  128
#define BMq   64
#define NSLOT (T_TOK*2)                 // 32768
#define NSLOT_PAD (NSLOT + NE*BMq)      // 33792
#define NBLK1 (NSLOT_PAD/BMq)           // 528

typedef _Float16 half8 __attribute__((ext_vector_type(8)));
typedef _Float16 half4 __attribute__((ext_vector_type(4)));
typedef float    f32x4 __attribute__((ext_vector_type(4)));

// ---------------- workspace layout (bytes) ----------------
// BASE region (identical to the passing round-3 layout):
#define WS_TOKE 0              // int2[T]    131072
#define WS_TOKW 131072         // float2[T]  131072
#define WS_CNT  262144         // int[16]
#define WS_CUR  262208         // int[16]
#define WS_OFF  262272         // int[17]
#define WS_STOK 262400         // int[NSLOT_PAD]   135168
#define WS_SW   397568         // float[NSLOT_PAD] 135168
#define WS_ABUF 532736         // _Float16[NSLOT_PAD*128]  8650752 -> 9183488
// FULL-tier extras (only touched when ws_size >= WS_FULL_END):
#define WS_TSLOT 9183488ULL    // int2[T]                 131072 -> 9314560
#define WS_WG16  9314560ULL    // half[16*128*1024]      4194304 -> 13508864
#define WS_WU16  13508864ULL   // half[16*1024*128]      4194304 -> 17703168
#define WS_X16   17703168ULL   // half[T*1024]          33554432 -> 51257600
#define WS_OBUF  51257600ULL   // half[NSLOT_PAD*1024]  69206016 -> 120463616
#define WS_FULL_END 120463616ULL

// ---------------- router: coalesced fp32 GEMV, top2, softmax ----------------
// 1 wave per token (2 tokens/wave). Lane l holds x[t][l*4..+4]; 16 expert
// partials in registers; butterfly reduce; lane0 top-2 (strict >, asc index).
template<bool WX>
__global__ __launch_bounds__(256) void router_k(const float* __restrict__ x,
                                                const float* __restrict__ Wr,
                                                int2* __restrict__ tok_e,
                                                float2* __restrict__ tok_w,
                                                _Float16* __restrict__ x16) {
    int wv = threadIdx.x >> 6, lane = threadIdx.x & 63;
#pragma unroll
    for (int i = 0; i < 2; ++i) {
        int t = blockIdx.x * 4 + wv + i * 8192;
        float acc[NE];
#pragma unroll
        for (int e = 0; e < NE; ++e) acc[e] = 0.f;
        const float4* xp = reinterpret_cast<const float4*>(x + (size_t)t * HDIM);
#pragma unroll
        for (int p = 0; p < 4; ++p) {
            int off = p * 64 + lane;                         // float4 index in row
            float4 xv = xp[off];
            if (WX) {
                half4 hv = {(_Float16)xv.x,(_Float16)xv.y,(_Float16)xv.z,(_Float16)xv.w};
                *reinterpret_cast<half4*>(x16 + (size_t)t * HDIM + off * 4) = hv;
            }
#pragma unroll
            for (int e = 0; e < NE; ++e) {
                float4 wv4 = *reinterpret_cast<const float4*>(Wr + (size_t)e * HDIM + off * 4);
                acc[e] += xv.x*wv4.x + xv.y*wv4.y + xv.z*wv4.z + xv.w*wv4.w;
            }
        }
#pragma unroll
        for (int e = 0; e < NE; ++e) {
#pragma unroll
            for (int m = 1; m < 64; m <<= 1)
                acc[e] += __shfl_xor(acc[e], m);
        }
        if (lane == 0) {
            float v1 = -1e30f, v2 = -1e30f; int i1 = 0, i2 = 0;
#pragma unroll
            for (int q = 0; q < NE; ++q) {
                float lv = acc[q];
                if (lv > v1)      { v2 = v1; i2 = i1; v1 = lv; i1 = q; }
                else if (lv > v2) { v2 = lv; i2 = q; }
            }
            float e2 = __expf(v2 - v1);
            float inv = 1.f / (1.f + e2);
            tok_e[t] = make_int2(i1, i2);
            tok_w[t] = make_float2(inv, e2 * inv);
        }
    }
}

// ---------------- weight fp32->fp16 pre-convert (FULL tier) ----------------
__global__ __launch_bounds__(256) void cvtw_k(const float* __restrict__ Wg,
                                              const float* __restrict__ Wu,
                                              _Float16* __restrict__ Wg16,
                                              _Float16* __restrict__ Wu16) {
    int i = blockIdx.x * 256 + threadIdx.x;        // 524288 float4 per array
    float4 g = reinterpret_cast<const float4*>(Wg)[i];
    float4 u = reinterpret_cast<const float4*>(Wu)[i];
    half4 gh = {(_Float16)g.x,(_Float16)g.y,(_Float16)g.z,(_Float16)g.w};
    half4 uh = {(_Float16)u.x,(_Float16)u.y,(_Float16)u.z,(_Float16)u.w};
    reinterpret_cast<half4*>(Wg16)[i] = gh;
    reinterpret_cast<half4*>(Wu16)[i] = uh;
}

// ---------------- per-expert token counts ----------------
__global__ __launch_bounds__(256) void count_k(const int2* __restrict__ tok_e,
                                               int* __restrict__ counts) {
    int e = blockIdx.x;
    int c = 0;
    for (int t = threadIdx.x; t < T_TOK; t += 256) {
        int2 te = tok_e[t];
        c += (te.x == e) + (te.y == e);
    }
    __shared__ int red[256];
    red[threadIdx.x] = c; __syncthreads();
    for (int s = 128; s > 0; s >>= 1) {
        if (threadIdx.x < s) red[threadIdx.x] += red[threadIdx.x + s];
        __syncthreads();
    }
    if (threadIdx.x == 0) counts[e] = red[0];
}

// ---------------- padded exclusive scan ----------------
__global__ void scan_k(const int* __restrict__ counts, int* __restrict__ offs) {
    if (threadIdx.x == 0) {
        int acc = 0;
        for (int e = 0; e < NE; ++e) {
            offs[e] = acc;
            acc += ((counts[e] + BMq - 1) / BMq) * BMq;
        }
        offs[NE] = acc;
    }
}

// ---------------- scatter token->slot ----------------
template<bool FULL>
__global__ __launch_bounds__(256) void scatter_k(const int2* __restrict__ tok_e,
                                                 const float2* __restrict__ tok_w,
                                                 const int* __restrict__ offs,
                                                 int* __restrict__ cursors,
                                                 int* __restrict__ slot_tok,
                                                 float* __restrict__ slot_w,
                                                 int2* __restrict__ tok_slots) {
    __shared__ int lcnt[NE];
    __shared__ int lbase[NE];
    if (threadIdx.x < NE) lcnt[threadIdx.x] = 0;
    __syncthreads();
    int t = blockIdx.x * 256 + threadIdx.x;
    int2 te = tok_e[t]; float2 tw = tok_w[t];
    int p0 = atomicAdd(&lcnt[te.x], 1);
    int p1 = atomicAdd(&lcnt[te.y], 1);
    __syncthreads();
    if (threadIdx.x < NE)
        lbase[threadIdx.x] = atomicAdd(&cursors[threadIdx.x], lcnt[threadIdx.x]);
    __syncthreads();
    int s0 = offs[te.x] + lbase[te.x] + p0;
    int s1 = offs[te.y] + lbase[te.y] + p1;
    slot_tok[s0] = t; slot_w[s0] = tw.x;
    slot_tok[s1] = t; slot_w[s1] = tw.y;
    if (FULL) tok_slots[t] = make_int2(s0, s1);
}

// ---------------- GEMM1: a = silu(x_gathered @ Wg[e]^T + bg[e]) ----------------
template<bool FULL>
__global__ __launch_bounds__(256) void gemm1_k(const float* __restrict__ x,
                                               const _Float16* __restrict__ x16,
                                               const float* __restrict__ Wg,
                                               const _Float16* __restrict__ Wg16,
                                               const float* __restrict__ bg,
                                               const int* __restrict__ offs,
                                               const int* __restrict__ slot_tok,
                                               _Float16* __restrict__ abuf) {
    __shared__ __align__(16) _Float16 As[64 * 64];
    __shared__ __align__(16) _Float16 Bs[128 * 64];
    __shared__ int tokLds[64];
    int row0 = blockIdx.x * BMq;
    if (row0 >= offs[NE]) return;
    int e = 0;
#pragma unroll
    for (int q = 1; q < NE; ++q) if (offs[q] <= row0) e = q;
    int tid = threadIdx.x;
    if (tid < 64) tokLds[tid] = slot_tok[row0 + tid];
    __syncthreads();
    int wv = tid >> 6, lane = tid & 63;
    f32x4 acc[4][2] = {};
    for (int kk = 0; kk < HDIM; kk += 64) {
        if (FULL) {
            // A: 64 rows x 8 half8 gathered from x16
#pragma unroll
            for (int j = 0; j < 2; ++j) {
                int idx = tid + j * 256;
                int r = idx >> 3, hq = idx & 7;
                int tok = tokLds[r];
                half8 v = {0,0,0,0,0,0,0,0};
                if (tok >= 0) v = *reinterpret_cast<const half8*>(x16 + (size_t)tok * HDIM + kk + hq * 8);
                *reinterpret_cast<half8*>(&As[r * 64 + ((hq * 8) ^ ((r & 7) << 3))]) = v;
            }
            // B: Wg16[e]: 128 rows x 8 half8
#pragma unroll
            for (int j = 0; j < 4; ++j) {
                int idx = tid + j * 256;
                int r = idx >> 3, hq = idx & 7;
                half8 v = *reinterpret_cast<const half8*>(Wg16 + (size_t)e * IDIM * HDIM + (size_t)r * HDIM + kk + hq * 8);
                *reinterpret_cast<half8*>(&Bs[r * 64 + ((hq * 8) ^ ((r & 7) << 3))]) = v;
            }
        } else {
#pragma unroll
            for (int j = 0; j < 4; ++j) {
                int idx = tid + j * 256;
                int r = idx >> 4, kq = idx & 15;
                int tok = tokLds[r];
                float4 v = make_float4(0.f, 0.f, 0.f, 0.f);
                if (tok >= 0) v = *reinterpret_cast<const float4*>(x + (size_t)tok * HDIM + kk + kq * 4);
                half4 hv = {(_Float16)v.x, (_Float16)v.y, (_Float16)v.z, (_Float16)v.w};
                *reinterpret_cast<half4*>(&As[r * 64 + ((kq * 4) ^ ((r & 7) << 3))]) = hv;
            }
#pragma unroll 4
            for (int j = 0; j < 8; ++j) {
                int idx = tid + j * 256;
                int r = idx >> 4, kq = idx & 15;
                float4 v = *reinterpret_cast<const float4*>(Wg + (size_t)e * IDIM * HDIM + (size_t)r * HDIM + kk + kq * 4);
                half4 hv = {(_Float16)v.x, (_Float16)v.y, (_Float16)v.z, (_Float16)v.w};
                *reinterpret_cast<half4*>(&Bs[r * 64 + ((kq * 4) ^ ((r & 7) << 3))]) = hv;
            }
        }
        __syncthreads();
#pragma unroll
        for (int ks = 0; ks < 64; ks += 32) {
            int c = ks + ((lane >> 4) << 3);
            half8 af[4], bf[2];
#pragma unroll
            for (int rt = 0; rt < 4; ++rt) {
                int r = rt * 16 + (lane & 15);
                af[rt] = *reinterpret_cast<const half8*>(&As[r * 64 + (c ^ ((r & 7) << 3))]);
            }
#pragma unroll
            for (int ct = 0; ct < 2; ++ct) {
                int r = wv * 32 + ct * 16 + (lane & 15);
                bf[ct] = *reinterpret_cast<const half8*>(&Bs[r * 64 + (c ^ ((r & 7) << 3))]);
            }
#pragma unroll
            for (int rt = 0; rt < 4; ++rt)
#pragma unroll
                for (int ct = 0; ct < 2; ++ct)
                    acc[rt][ct] = __builtin_amdgcn_mfma_f32_16x16x32_f16(af[rt], bf[ct], acc[rt][ct], 0, 0, 0);
        }
        __syncthreads();
    }
#pragma unroll
    for (int rt = 0; rt < 4; ++rt)
#pragma unroll
        for (int ct = 0; ct < 2; ++ct) {
            int i = wv * 32 + ct * 16 + (lane & 15);
            float bgv = bg[e * IDIM + i];
#pragma unroll
            for (int j = 0; j < 4; ++j) {
                int m = rt * 16 + ((lane >> 4) << 2) + j;
                if (tokLds[m] >= 0) {
                    float v = acc[rt][ct][j] + bgv;
                    float sv = v / (1.f + __expf(-v));
                    abuf[(size_t)(row0 + m) * IDIM + i] = (_Float16)sv;
                }
            }
        }
}

// ---------------- GEMM2: O_slot = a @ Wu[e]^T  (FULL: store; BASE: atomic) ----
template<bool FULL>
__global__ __launch_bounds__(256) void gemm2_k(const _Float16* __restrict__ abuf,
                                               const float* __restrict__ Wu,
                                               const _Float16* __restrict__ Wu16,
                                               const float* __restrict__ bu,
                                               const int* __restrict__ offs,
                                               const int* __restrict__ slot_tok,
                                               const float* __restrict__ slot_w,
                                               float* __restrict__ out,
                                               _Float16* __restrict__ Obuf) {
    __shared__ __align__(16) _Float16 As[64 * 128];
    __shared__ __align__(16) _Float16 Bs[128 * 128];
    __shared__ int   tokLds[64];
    __shared__ float wLds[64];
    int row0 = blockIdx.x * BMq;
    if (row0 >= offs[NE]) return;
    int h0 = blockIdx.y * 128;
    int e = 0;
#pragma unroll
    for (int q = 1; q < NE; ++q) if (offs[q] <= row0) e = q;
    int tid = threadIdx.x;
    if (tid < 64) { tokLds[tid] = slot_tok[row0 + tid]; wLds[tid] = slot_w[row0 + tid]; }
    // A: abuf rows, 64 x 16 half8
#pragma unroll
    for (int j = 0; j < 4; ++j) {
        int idx = tid + j * 256;
        int r = idx >> 4, hq = idx & 15;
        half8 v = *reinterpret_cast<const half8*>(abuf + (size_t)(row0 + r) * IDIM + hq * 8);
        *reinterpret_cast<half8*>(&As[r * 128 + ((hq * 8) ^ ((r & 7) << 3))]) = v;
    }
    if (FULL) {
#pragma unroll
        for (int j = 0; j < 8; ++j) {
            int idx = tid + j * 256;
            int r = idx >> 4, fq = idx & 15;
            half8 v = *reinterpret_cast<const half8*>(Wu16 + (size_t)e * HDIM * IDIM + (size_t)(h0 + r) * IDIM + fq * 8);
            *reinterpret_cast<half8*>(&Bs[r * 128 + ((fq * 8) ^ ((r & 7) << 3))]) = v;
        }
    } else {
#pragma unroll 4
        for (int j = 0; j < 16; ++j) {
            int idx = tid + j * 256;
            int r = idx >> 5, fq = idx & 31;
            float4 v = *reinterpret_cast<const float4*>(Wu + (size_t)e * HDIM * IDIM + (size_t)(h0 + r) * IDIM + fq * 4);
            half4 hv = {(_Float16)v.x, (_Float16)v.y, (_Float16)v.z, (_Float16)v.w};
            *reinterpret_cast<half4*>(&Bs[r * 128 + ((fq * 4) ^ ((r & 7) << 3))]) = hv;
        }
    }
    __syncthreads();
    int wv = tid >> 6, lane = tid & 63;
    f32x4 acc[4][2] = {};
#pragma unroll
    for (int ks = 0; ks < 128; ks += 32) {
        int c = ks + ((lane >> 4) << 3);
        half8 af[4], bf[2];
#pragma unroll
        for (int rt = 0; rt < 4; ++rt) {
            int r = rt * 16 + (lane & 15);
            af[rt] = *reinterpret_cast<const half8*>(&As[r * 128 + (c ^ ((r & 7) << 3))]);
        }
#pragma unroll
        for (int ct = 0; ct < 2; ++ct) {
            int r = wv * 32 + ct * 16 + (lane & 15);
            bf[ct] = *reinterpret_cast<const half8*>(&Bs[r * 128 + (c ^ ((r & 7) << 3))]);
        }
#pragma unroll
        for (int rt = 0; rt < 4; ++rt)
#pragma unroll
            for (int ct = 0; ct < 2; ++ct)
                acc[rt][ct] = __builtin_amdgcn_mfma_f32_16x16x32_f16(af[rt], bf[ct], acc[rt][ct], 0, 0, 0);
    }
#pragma unroll
    for (int rt = 0; rt < 4; ++rt)
#pragma unroll
        for (int ct = 0; ct < 2; ++ct) {
            int h = h0 + wv * 32 + ct * 16 + (lane & 15);
#pragma unroll
            for (int j = 0; j < 4; ++j) {
                int m = rt * 16 + ((lane >> 4) << 2) + j;
                if (FULL) {
                    Obuf[(size_t)(row0 + m) * HDIM + h] = (_Float16)acc[rt][ct][j];
                } else {
                    int tok = tokLds[m];
                    if (tok >= 0)
                        atomicAdd(out + (size_t)tok * HDIM + h,
                                  (acc[rt][ct][j] + bu[e * HDIM + h]) * wLds[m]);
                }
            }
        }
}

// ---------------- combine (FULL): out[t] = w1*(O1+bu[e1]) + w2*(O2+bu[e2]) ----
__global__ __launch_bounds__(256) void combine_k(const _Float16* __restrict__ Obuf,
                                                 const float* __restrict__ bu,
                                                 const int2* __restrict__ tok_slots,
                                                 const int2* __restrict__ tok_e,
                                                 const float2* __restrict__ tok_w,
                                                 float* __restrict__ out) {
    int wv = threadIdx.x >> 6, lane = threadIdx.x & 63;
    int t = blockIdx.x * 4 + wv;
    int2   sl = tok_slots[t];
    int2   te = tok_e[t];
    float2 tw = tok_w[t];
    const _Float16* O1 = Obuf + (size_t)sl.x * HDIM;
    const _Float16* O2 = Obuf + (size_t)sl.y * HDIM;
    const float* b1 = bu + (size_t)te.x * HDIM;
    const float* b2 = bu + (size_t)te.y * HDIM;
    float* op = out + (size_t)t * HDIM;
#pragma unroll
    for (int q = 0; q < 4; ++q) {
        int h = q * 256 + lane * 4;
        half4  a1 = *reinterpret_cast<const half4*>(O1 + h);
        half4  a2 = *reinterpret_cast<const half4*>(O2 + h);
        float4 v1 = *reinterpret_cast<const float4*>(b1 + h);
        float4 v2 = *reinterpret_cast<const float4*>(b2 + h);
        float4 o;
        o.x = tw.x * ((float)a1[0] + v1.x) + tw.y * ((float)a2[0] + v2.x);
        o.y = tw.x * ((float)a1[1] + v1.y) + tw.y * ((float)a2[1] + v2.y);
        o.z = tw.x * ((float)a1[2] + v1.z) + tw.y * ((float)a2[2] + v2.z);
        o.w = tw.x * ((float)a1[3] + v1.w) + tw.y * ((float)a2[3] + v2.w);
        *reinterpret_cast<float4*>(op + h) = o;
    }
}

extern "C" void kernel_launch(void* const* d_in, const int* in_sizes, int n_in,
                              void* d_out, int out_size, void* d_ws, size_t ws_size,
                              hipStream_t stream) {
    const float* x  = (const float*)d_in[0];
    const float* Wr = (const float*)d_in[1];
    const float* Wg = (const float*)d_in[2];
    const float* bg = (const float*)d_in[3];
    const float* Wu = (const float*)d_in[4];
    const float* bu = (const float*)d_in[5];
    float* out = (float*)d_out;
    char* ws = (char*)d_ws;

    int2*      tok_e    = (int2*)(ws + WS_TOKE);
    float2*    tok_w    = (float2*)(ws + WS_TOKW);
    int*       counts   = (int*)(ws + WS_CNT);
    int*       cursors  = (int*)(ws + WS_CUR);
    int*       offs     = (int*)(ws + WS_OFF);
    int*       slot_tok = (int*)(ws + WS_STOK);
    float*     slot_w   = (float*)(ws + WS_SW);
    _Float16*  abuf     = (_Float16*)(ws + WS_ABUF);
    int2*      tok_slots= (int2*)(ws + WS_TSLOT);
    _Float16*  Wg16     = (_Float16*)(ws + WS_WG16);
    _Float16*  Wu16     = (_Float16*)(ws + WS_WU16);
    _Float16*  x16      = (_Float16*)(ws + WS_X16);
    _Float16*  Obuf     = (_Float16*)(ws + WS_OBUF);

    const bool full = (ws_size >= WS_FULL_END);   // constant per process -> capture-safe

    hipMemsetAsync(ws + WS_CNT, 0, 256, stream);
    hipMemsetAsync(slot_tok, 0xFF, NSLOT_PAD * sizeof(int), stream);

    if (full) {
        cvtw_k   <<<2048, 256, 0, stream>>>(Wg, Wu, Wg16, Wu16);
        router_k<true><<<T_TOK/8, 256, 0, stream>>>(x, Wr, tok_e, tok_w, x16);
        count_k  <<<NE, 256, 0, stream>>>(tok_e, counts);
        scan_k   <<<1, 64, 0, stream>>>(counts, offs);
        scatter_k<true><<<T_TOK/256, 256, 0, stream>>>(tok_e, tok_w, offs, cursors, slot_tok, slot_w, tok_slots);
        gemm1_k<true><<<NBLK1, 256, 0, stream>>>(x, x16, Wg, Wg16, bg, offs, slot_tok, abuf);
        dim3 g2(NBLK1, 8);
        gemm2_k<true><<<g2, 256, 0, stream>>>(abuf, Wu, Wu16, bu, offs, slot_tok, slot_w, out, Obuf);
        combine_k<<<T_TOK/4, 256, 0, stream>>>(Obuf, bu, tok_slots, tok_e, tok_w, out);
    } else {
        hipMemsetAsync(d_out, 0, (size_t)T_TOK * HDIM * sizeof(float), stream);
        router_k<false><<<T_TOK/8, 256, 0, stream>>>(x, Wr, tok_e, tok_w, nullptr);
        count_k  <<<NE, 256, 0, stream>>>(tok_e, counts);
        scan_k   <<<1, 64, 0, stream>>>(counts, offs);
        scatter_k<false><<<T_TOK/256, 256, 0, stream>>>(tok_e, tok_w, offs, cursors, slot_tok, slot_w, nullptr);
        gemm1_k<false><<<NBLK1, 256, 0, stream>>>(x, nullptr, Wg, nullptr, bg, offs, slot_tok, abuf);
        dim3 g2(NBLK1, 8);
        gemm2_k<false><<<g2, 256, 0, stream>>>(abuf, Wu, nullptr, bu, offs, slot_tok, slot_w, out, nullptr);
    }
}

// Round 6
// 274.432 us; speedup vs baseline: 1.7725x; 1.0012x over previous
//
#include <hip/hip_runtime.h>
#include <hip/hip_fp16.h>

// Problem constants
#define T_TOK 16384
#define HDIM  1024
#define NE    16
#define IDIM  128
#define BMq   64
#define NSLOT (T_TOK*2)                 // 32768
#define NSLOT_PAD (NSLOT + NE*BMq)      // 33792
#define NBLK1 (NSLOT_PAD/BMq)           // 528

typedef _Float16 half8 __attribute__((ext_vector_type(8)));
typedef _Float16 half4 __attribute__((ext_vector_type(4)));
typedef float    f32x4 __attribute__((ext_vector_type(4)));

// ---------------- workspace layout (bytes) ----------------
#define WS_TOKE 0              // int2[T]    131072
#define WS_TOKW 131072         // float2[T]  131072
#define WS_CNT  262144         // int[16]
#define WS_CUR  262208         // int[16]
#define WS_OFF  262272         // int[17]
#define WS_STOK 262400         // int[NSLOT_PAD]   135168
#define WS_SW   397568         // float[NSLOT_PAD] 135168
#define WS_ABUF 532736         // _Float16[NSLOT_PAD*128]  8650752 -> 9183488
// FULL-tier extras:
#define WS_TSLOT 9183488ULL    // int2[T]                 131072 -> 9314560
#define WS_X16   17703168ULL   // half[T*1024]          33554432 -> 51257600
#define WS_OBUF  51257600ULL   // half[NSLOT_PAD*1024]  69206016 -> 120463616
#define WS_FULL_END 120463616ULL

__device__ inline void hilo8(float4 a, float4 b, half8& h, half8& l) {
    float f[8] = {a.x, a.y, a.z, a.w, b.x, b.y, b.z, b.w};
#pragma unroll
    for (int i = 0; i < 8; ++i) {
        _Float16 hi = (_Float16)f[i];
        h[i] = hi;
        l[i] = (_Float16)((f[i] - (float)hi) * 2048.f);
    }
}

// ---------------- router: K-split MFMA logits (hi/lo fp16 = fp32-accurate) ----
// Block: 4 waves x 16 tokens. Wave w covers K [w*256,(w+1)*256) via 8 MFMAs.
// LDS-reduce 4 partials; 16 threads do top-2 + softmax. Fused: x16 write,
// per-expert counts (LDS hist -> global atomics), slot_tok=-1 init.
template<bool WX>
__global__ __launch_bounds__(256) void router_k(const float* __restrict__ x,
                                                const float* __restrict__ Wr,
                                                int2* __restrict__ tok_e,
                                                float2* __restrict__ tok_w,
                                                _Float16* __restrict__ x16,
                                                int* __restrict__ counts,
                                                int* __restrict__ slot_tok) {
    __shared__ float red[4][16][16];
    __shared__ int hist[NE];
    int tid = threadIdx.x;
    int wv = tid >> 6, lane = tid & 63;
    int tile0 = blockIdx.x * 16;

    int gi = blockIdx.x * 256 + tid;                 // slot_tok init (1024*256 >= NSLOT_PAD)
    if (gi < NSLOT_PAD) slot_tok[gi] = -1;
    if (tid < NE) hist[tid] = 0;

    int row = lane & 15;                             // token row == expert row
    int kq  = (lane >> 4) * 8;
    const float* xrow = x  + (size_t)(tile0 + row) * HDIM;
    const float* wrow = Wr + (size_t)row * HDIM;
    f32x4 accM = {0.f,0.f,0.f,0.f};
    f32x4 accC = {0.f,0.f,0.f,0.f};
#pragma unroll
    for (int s = 0; s < 8; ++s) {
        int k = wv * 256 + s * 32 + kq;
        float4 xa = *reinterpret_cast<const float4*>(xrow + k);
        float4 xb = *reinterpret_cast<const float4*>(xrow + k + 4);
        float4 wa = *reinterpret_cast<const float4*>(wrow + k);
        float4 wb = *reinterpret_cast<const float4*>(wrow + k + 4);
        half8 xh, xl, wh, wl;
        hilo8(xa, xb, xh, xl);
        hilo8(wa, wb, wh, wl);
        if (WX)
            *reinterpret_cast<half8*>(x16 + (size_t)(tile0 + row) * HDIM + k) = xh;
        accM = __builtin_amdgcn_mfma_f32_16x16x32_f16(xh, wh, accM, 0, 0, 0);
        accC = __builtin_amdgcn_mfma_f32_16x16x32_f16(xh, wl, accC, 0, 0, 0);
        accC = __builtin_amdgcn_mfma_f32_16x16x32_f16(xl, wh, accC, 0, 0, 0);
    }
    // C layout: token = (lane>>4)*4+j, expert = lane&15 (HW-verified)
#pragma unroll
    for (int j = 0; j < 4; ++j)
        red[wv][(lane >> 4) * 4 + j][lane & 15] = accM[j] + accC[j] * (1.f/2048.f);
    __syncthreads();
    if (tid < 16) {
        float v1 = -1e30f, v2 = -1e30f; int i1 = 0, i2 = 0;
#pragma unroll
        for (int q = 0; q < NE; ++q) {
            float lv = red[0][tid][q] + red[1][tid][q] + red[2][tid][q] + red[3][tid][q];
            if (lv > v1)      { v2 = v1; i2 = i1; v1 = lv; i1 = q; }
            else if (lv > v2) { v2 = lv; i2 = q; }
        }
        int t = tile0 + tid;
        float e2 = __expf(v2 - v1);
        float inv = 1.f / (1.f + e2);
        tok_e[t] = make_int2(i1, i2);
        tok_w[t] = make_float2(inv, e2 * inv);
        atomicAdd(&hist[i1], 1);
        atomicAdd(&hist[i2], 1);
    }
    __syncthreads();
    if (tid < NE) { int c = hist[tid]; if (c) atomicAdd(&counts[tid], c); }
}

// ---------------- padded exclusive scan ----------------
__global__ void scan_k(const int* __restrict__ counts, int* __restrict__ offs) {
    if (threadIdx.x == 0) {
        int acc = 0;
        for (int e = 0; e < NE; ++e) {
            offs[e] = acc;
            acc += ((counts[e] + BMq - 1) / BMq) * BMq;
        }
        offs[NE] = acc;
    }
}

// ---------------- scatter token->slot ----------------
template<bool FULL>
__global__ __launch_bounds__(256) void scatter_k(const int2* __restrict__ tok_e,
                                                 const float2* __restrict__ tok_w,
                                                 const int* __restrict__ offs,
                                                 int* __restrict__ cursors,
                                                 int* __restrict__ slot_tok,
                                                 float* __restrict__ slot_w,
                                                 int2* __restrict__ tok_slots) {
    __shared__ int lcnt[NE];
    __shared__ int lbase[NE];
    if (threadIdx.x < NE) lcnt[threadIdx.x] = 0;
    __syncthreads();
    int t = blockIdx.x * 256 + threadIdx.x;
    int2 te = tok_e[t]; float2 tw = tok_w[t];
    int p0 = atomicAdd(&lcnt[te.x], 1);
    int p1 = atomicAdd(&lcnt[te.y], 1);
    __syncthreads();
    if (threadIdx.x < NE)
        lbase[threadIdx.x] = atomicAdd(&cursors[threadIdx.x], lcnt[threadIdx.x]);
    __syncthreads();
    int s0 = offs[te.x] + lbase[te.x] + p0;
    int s1 = offs[te.y] + lbase[te.y] + p1;
    slot_tok[s0] = t; slot_w[s0] = tw.x;
    slot_tok[s1] = t; slot_w[s1] = tw.y;
    if (FULL) tok_slots[t] = make_int2(s0, s1);
}

// ---------------- GEMM1: a = silu(x_gathered @ Wg[e]^T + bg[e]) ----------------
template<bool FULL>
__global__ __launch_bounds__(256) void gemm1_k(const float* __restrict__ x,
                                               const _Float16* __restrict__ x16,
                                               const float* __restrict__ Wg,
                                               const float* __restrict__ bg,
                                               const int* __restrict__ offs,
                                               const int* __restrict__ slot_tok,
                                               _Float16* __restrict__ abuf) {
    __shared__ __align__(16) _Float16 As[64 * 64];
    __shared__ __align__(16) _Float16 Bs[128 * 64];
    __shared__ int tokLds[64];
    int row0 = blockIdx.x * BMq;
    if (row0 >= offs[NE]) return;
    int e = 0;
#pragma unroll
    for (int q = 1; q < NE; ++q) if (offs[q] <= row0) e = q;
    int tid = threadIdx.x;
    if (tid < 64) tokLds[tid] = slot_tok[row0 + tid];
    __syncthreads();
    int wv = tid >> 6, lane = tid & 63;
    f32x4 acc[4][2] = {};
    for (int kk = 0; kk < HDIM; kk += 64) {
        if (FULL) {
            // A: 64 rows x 8 half8 gathered from x16
#pragma unroll
            for (int j = 0; j < 2; ++j) {
                int idx = tid + j * 256;
                int r = idx >> 3, hq = idx & 7;
                int tok = tokLds[r];
                half8 v = {0,0,0,0,0,0,0,0};
                if (tok >= 0) v = *reinterpret_cast<const half8*>(x16 + (size_t)tok * HDIM + kk + hq * 8);
                *reinterpret_cast<half8*>(&As[r * 64 + ((hq * 8) ^ ((r & 7) << 3))]) = v;
            }
        } else {
#pragma unroll
            for (int j = 0; j < 4; ++j) {
                int idx = tid + j * 256;
                int r = idx >> 4, kq = idx & 15;
                int tok = tokLds[r];
                float4 v = make_float4(0.f, 0.f, 0.f, 0.f);
                if (tok >= 0) v = *reinterpret_cast<const float4*>(x + (size_t)tok * HDIM + kk + kq * 4);
                half4 hv = {(_Float16)v.x, (_Float16)v.y, (_Float16)v.z, (_Float16)v.w};
                *reinterpret_cast<half4*>(&As[r * 64 + ((kq * 4) ^ ((r & 7) << 3))]) = hv;
            }
        }
        // B: Wg[e][i][kk..kk+63] fp32 -> fp16: 128 rows x 16 float4
#pragma unroll 4
        for (int j = 0; j < 8; ++j) {
            int idx = tid + j * 256;
            int r = idx >> 4, kq = idx & 15;
            float4 v = *reinterpret_cast<const float4*>(Wg + (size_t)e * IDIM * HDIM + (size_t)r * HDIM + kk + kq * 4);
            half4 hv = {(_Float16)v.x, (_Float16)v.y, (_Float16)v.z, (_Float16)v.w};
            *reinterpret_cast<half4*>(&Bs[r * 64 + ((kq * 4) ^ ((r & 7) << 3))]) = hv;
        }
        __syncthreads();
#pragma unroll
        for (int ks = 0; ks < 64; ks += 32) {
            int c = ks + ((lane >> 4) << 3);
            half8 af[4], bf[2];
#pragma unroll
            for (int rt = 0; rt < 4; ++rt) {
                int r = rt * 16 + (lane & 15);
                af[rt] = *reinterpret_cast<const half8*>(&As[r * 64 + (c ^ ((r & 7) << 3))]);
            }
#pragma unroll
            for (int ct = 0; ct < 2; ++ct) {
                int r = wv * 32 + ct * 16 + (lane & 15);
                bf[ct] = *reinterpret_cast<const half8*>(&Bs[r * 64 + (c ^ ((r & 7) << 3))]);
            }
#pragma unroll
            for (int rt = 0; rt < 4; ++rt)
#pragma unroll
                for (int ct = 0; ct < 2; ++ct)
                    acc[rt][ct] = __builtin_amdgcn_mfma_f32_16x16x32_f16(af[rt], bf[ct], acc[rt][ct], 0, 0, 0);
        }
        __syncthreads();
    }
#pragma unroll
    for (int rt = 0; rt < 4; ++rt)
#pragma unroll
        for (int ct = 0; ct < 2; ++ct) {
            int i = wv * 32 + ct * 16 + (lane & 15);
            float bgv = bg[e * IDIM + i];
#pragma unroll
            for (int j = 0; j < 4; ++j) {
                int m = rt * 16 + ((lane >> 4) << 2) + j;
                if (tokLds[m] >= 0) {
                    float v = acc[rt][ct][j] + bgv;
                    float sv = v / (1.f + __expf(-v));
                    abuf[(size_t)(row0 + m) * IDIM + i] = (_Float16)sv;
                }
            }
        }
}

// ---------------- GEMM2: O_slot = a @ Wu[e]^T + bu[e] (FULL) / atomic (BASE) ----
template<bool FULL>
__global__ __launch_bounds__(256) void gemm2_k(const _Float16* __restrict__ abuf,
                                               const float* __restrict__ Wu,
                                               const float* __restrict__ bu,
                                               const int* __restrict__ offs,
                                               const int* __restrict__ slot_tok,
                                               const float* __restrict__ slot_w,
                                               float* __restrict__ out,
                                               _Float16* __restrict__ Obuf) {
    __shared__ __align__(16) _Float16 As[64 * 128];
    __shared__ __align__(16) _Float16 Bs[128 * 128];
    __shared__ int   tokLds[64];
    __shared__ float wLds[64];
    int row0 = blockIdx.x * BMq;
    if (row0 >= offs[NE]) return;
    int h0 = blockIdx.y * 128;
    int e = 0;
#pragma unroll
    for (int q = 1; q < NE; ++q) if (offs[q] <= row0) e = q;
    int tid = threadIdx.x;
    if (tid < 64) { tokLds[tid] = slot_tok[row0 + tid]; wLds[tid] = slot_w[row0 + tid]; }
    // A: abuf rows, 64 x 16 half8
#pragma unroll
    for (int j = 0; j < 4; ++j) {
        int idx = tid + j * 256;
        int r = idx >> 4, hq = idx & 15;
        half8 v = *reinterpret_cast<const half8*>(abuf + (size_t)(row0 + r) * IDIM + hq * 8);
        *reinterpret_cast<half8*>(&As[r * 128 + ((hq * 8) ^ ((r & 7) << 3))]) = v;
    }
    // B: Wu[e][h0+r][i] fp32 -> fp16: 128 rows x 32 float4
#pragma unroll 4
    for (int j = 0; j < 16; ++j) {
        int idx = tid + j * 256;
        int r = idx >> 5, fq = idx & 31;
        float4 v = *reinterpret_cast<const float4*>(Wu + (size_t)e * HDIM * IDIM + (size_t)(h0 + r) * IDIM + fq * 4);
        half4 hv = {(_Float16)v.x, (_Float16)v.y, (_Float16)v.z, (_Float16)v.w};
        *reinterpret_cast<half4*>(&Bs[r * 128 + ((fq * 4) ^ ((r & 7) << 3))]) = hv;
    }
    __syncthreads();
    int wv = tid >> 6, lane = tid & 63;
    f32x4 acc[4][2] = {};
#pragma unroll
    for (int ks = 0; ks < 128; ks += 32) {
        int c = ks + ((lane >> 4) << 3);
        half8 af[4], bf[2];
#pragma unroll
        for (int rt = 0; rt < 4; ++rt) {
            int r = rt * 16 + (lane & 15);
            af[rt] = *reinterpret_cast<const half8*>(&As[r * 128 + (c ^ ((r & 7) << 3))]);
        }
#pragma unroll
        for (int ct = 0; ct < 2; ++ct) {
            int r = wv * 32 + ct * 16 + (lane & 15);
            bf[ct] = *reinterpret_cast<const half8*>(&Bs[r * 128 + (c ^ ((r & 7) << 3))]);
        }
#pragma unroll
        for (int rt = 0; rt < 4; ++rt)
#pragma unroll
            for (int ct = 0; ct < 2; ++ct)
                acc[rt][ct] = __builtin_amdgcn_mfma_f32_16x16x32_f16(af[rt], bf[ct], acc[rt][ct], 0, 0, 0);
    }
#pragma unroll
    for (int rt = 0; rt < 4; ++rt)
#pragma unroll
        for (int ct = 0; ct < 2; ++ct) {
            int h = h0 + wv * 32 + ct * 16 + (lane & 15);
            float buv = bu[e * HDIM + h];
#pragma unroll
            for (int j = 0; j < 4; ++j) {
                int m = rt * 16 + ((lane >> 4) << 2) + j;
                if (FULL) {
                    Obuf[(size_t)(row0 + m) * HDIM + h] = (_Float16)(acc[rt][ct][j] + buv);
                } else {
                    int tok = tokLds[m];
                    if (tok >= 0)
                        atomicAdd(out + (size_t)tok * HDIM + h,
                                  (acc[rt][ct][j] + buv) * wLds[m]);
                }
            }
        }
}

// ---------------- combine (FULL): out[t] = w1*O1 + w2*O2 ----------------
__global__ __launch_bounds__(256) void combine_k(const _Float16* __restrict__ Obuf,
                                                 const int2* __restrict__ tok_slots,
                                                 const float2* __restrict__ tok_w,
                                                 float* __restrict__ out) {
    int wv = threadIdx.x >> 6, lane = threadIdx.x & 63;
    int t = blockIdx.x * 4 + wv;
    int2   sl = tok_slots[t];
    float2 tw = tok_w[t];
    const _Float16* O1 = Obuf + (size_t)sl.x * HDIM;
    const _Float16* O2 = Obuf + (size_t)sl.y * HDIM;
    float* op = out + (size_t)t * HDIM;
#pragma unroll
    for (int q = 0; q < 4; ++q) {
        int h = q * 256 + lane * 4;
        half4  a1 = *reinterpret_cast<const half4*>(O1 + h);
        half4  a2 = *reinterpret_cast<const half4*>(O2 + h);
        float4 o;
        o.x = tw.x * (float)a1[0] + tw.y * (float)a2[0];
        o.y = tw.x * (float)a1[1] + tw.y * (float)a2[1];
        o.z = tw.x * (float)a1[2] + tw.y * (float)a2[2];
        o.w = tw.x * (float)a1[3] + tw.y * (float)a2[3];
        *reinterpret_cast<float4*>(op + h) = o;
    }
}

extern "C" void kernel_launch(void* const* d_in, const int* in_sizes, int n_in,
                              void* d_out, int out_size, void* d_ws, size_t ws_size,
                              hipStream_t stream) {
    const float* x  = (const float*)d_in[0];
    const float* Wr = (const float*)d_in[1];
    const float* Wg = (const float*)d_in[2];
    const float* bg = (const float*)d_in[3];
    const float* Wu = (const float*)d_in[4];
    const float* bu = (const float*)d_in[5];
    float* out = (float*)d_out;
    char* ws = (char*)d_ws;

    int2*      tok_e    = (int2*)(ws + WS_TOKE);
    float2*    tok_w    = (float2*)(ws + WS_TOKW);
    int*       counts   = (int*)(ws + WS_CNT);
    int*       cursors  = (int*)(ws + WS_CUR);
    int*       offs     = (int*)(ws + WS_OFF);
    int*       slot_tok = (int*)(ws + WS_STOK);
    float*     slot_w   = (float*)(ws + WS_SW);
    _Float16*  abuf     = (_Float16*)(ws + WS_ABUF);
    int2*      tok_slots= (int2*)(ws + WS_TSLOT);
    _Float16*  x16      = (_Float16*)(ws + WS_X16);
    _Float16*  Obuf     = (_Float16*)(ws + WS_OBUF);

    const bool full = (ws_size >= WS_FULL_END);   // constant per process -> capture-safe

    hipMemsetAsync(ws + WS_CNT, 0, 256, stream);  // counts+cursors

    if (full) {
        router_k<true><<<T_TOK/16, 256, 0, stream>>>(x, Wr, tok_e, tok_w, x16, counts, slot_tok);
        scan_k   <<<1, 64, 0, stream>>>(counts, offs);
        scatter_k<true><<<T_TOK/256, 256, 0, stream>>>(tok_e, tok_w, offs, cursors, slot_tok, slot_w, tok_slots);
        gemm1_k<true><<<NBLK1, 256, 0, stream>>>(x, x16, Wg, bg, offs, slot_tok, abuf);
        dim3 g2(NBLK1, 8);
        gemm2_k<true><<<g2, 256, 0, stream>>>(abuf, Wu, bu, offs, slot_tok, slot_w, out, Obuf);
        combine_k<<<T_TOK/4, 256, 0, stream>>>(Obuf, tok_slots, tok_w, out);
    } else {
        hipMemsetAsync(d_out, 0, (size_t)T_TOK * HDIM * sizeof(float), stream);
        router_k<false><<<T_TOK/16, 256, 0, stream>>>(x, Wr, tok_e, tok_w, nullptr, counts, slot_tok);
        scan_k   <<<1, 64, 0, stream>>>(counts, offs);
        scatter_k<false><<<T_TOK/256, 256, 0, stream>>>(tok_e, tok_w, offs, cursors, slot_tok, slot_w, nullptr);
        gemm1_k<false><<<NBLK1, 256, 0, stream>>>(x, nullptr, Wg, bg, offs, slot_tok, abuf);
        dim3 g2(NBLK1, 8);
        gemm2_k<false><<<g2, 256, 0, stream>>>(abuf, Wu, bu, offs, slot_tok, slot_w, out, nullptr);
    }
}

// Round 8
// 245.642 us; speedup vs baseline: 1.9803x; 1.1172x over previous
//
#include <hip/hip_runtime.h>
#include <hip/hip_fp16.h>

// Problem constants
#define T_TOK 16384
#define HDIM  1024
#define NE    16
#define IDIM  128
#define BMq   64
#define NSLOT (T_TOK*2)                 // 32768
#define NSLOT_PAD (NSLOT + NE*BMq)      // 33792
#define NBLK1 (NSLOT_PAD/BMq)           // 528

typedef _Float16 half8 __attribute__((ext_vector_type(8)));
typedef _Float16 half4 __attribute__((ext_vector_type(4)));
typedef float    f32x4 __attribute__((ext_vector_type(4)));

// ---------------- workspace layout (bytes) ----------------
#define WS_TOKE 0              // int2[T]    131072
#define WS_TOKW 131072         // float2[T]  131072
#define WS_CNT  262144         // int[16]
#define WS_CUR  262208         // int[16]
#define WS_OFF  262272         // int[17] (unused now)
#define WS_STOK 262400         // int[NSLOT_PAD]   135168
#define WS_SW   397568         // float[NSLOT_PAD] 135168
#define WS_ABUF 532736         // _Float16[NSLOT_PAD*128]  8650752 -> 9183488
// FULL-tier extras:
#define WS_TSLOT 9183488ULL    // int2[T]                 131072 -> 9314560
#define WS_WG16  9314560ULL    // half[16*128*1024]      4194304 -> 13508864
#define WS_WU16  13508864ULL   // half[16*1024*128]      4194304 -> 17703168
#define WS_X16   17703168ULL   // half[T*1024]          33554432 -> 51257600
#define WS_OBUF  51257600ULL   // half[NSLOT_PAD*1024]  69206016 -> 120463616
#define WS_FULL_END 120463616ULL

__device__ inline void hilo8(float4 a, float4 b, half8& h, half8& l) {
    float f[8] = {a.x, a.y, a.z, a.w, b.x, b.y, b.z, b.w};
#pragma unroll
    for (int i = 0; i < 8; ++i) {
        _Float16 hi = (_Float16)f[i];
        h[i] = hi;
        l[i] = (_Float16)((f[i] - (float)hi) * 2048.f);
    }
}

// expert index + padded total from counts (per-thread, L2-hot)
__device__ inline void expert_of(const int* __restrict__ counts, int row0,
                                 int& e, int& total) {
    int acc = 0; e = 0;
#pragma unroll
    for (int q = 0; q < NE; ++q) {
        int nx = acc + ((counts[q] + BMq - 1) / BMq) * BMq;
        if (nx <= row0) e = q + 1;
        acc = nx;
    }
    total = acc;
}

// ---------------- router: K-split MFMA logits (hi/lo fp16 = fp32-accurate) ----
template<bool WX>
__global__ __launch_bounds__(256) void router_k(const float* __restrict__ x,
                                                const float* __restrict__ Wr,
                                                int2* __restrict__ tok_e,
                                                float2* __restrict__ tok_w,
                                                _Float16* __restrict__ x16,
                                                int* __restrict__ counts,
                                                int* __restrict__ slot_tok) {
    __shared__ float red[4][16][16];
    __shared__ int hist[NE];
    int tid = threadIdx.x;
    int wv = tid >> 6, lane = tid & 63;
    int tile0 = blockIdx.x * 16;

    int gi = blockIdx.x * 256 + tid;                 // slot_tok init
    if (gi < NSLOT_PAD) slot_tok[gi] = -1;
    if (tid < NE) hist[tid] = 0;

    int row = lane & 15;
    int kq  = (lane >> 4) * 8;
    const float* xrow = x  + (size_t)(tile0 + row) * HDIM;
    const float* wrow = Wr + (size_t)row * HDIM;
    f32x4 accM = {0.f,0.f,0.f,0.f};
    f32x4 accC = {0.f,0.f,0.f,0.f};
#pragma unroll
    for (int s = 0; s < 8; ++s) {
        int k = wv * 256 + s * 32 + kq;
        float4 xa = *reinterpret_cast<const float4*>(xrow + k);
        float4 xb = *reinterpret_cast<const float4*>(xrow + k + 4);
        float4 wa = *reinterpret_cast<const float4*>(wrow + k);
        float4 wb = *reinterpret_cast<const float4*>(wrow + k + 4);
        half8 xh, xl, wh, wl;
        hilo8(xa, xb, xh, xl);
        hilo8(wa, wb, wh, wl);
        if (WX)
            *reinterpret_cast<half8*>(x16 + (size_t)(tile0 + row) * HDIM + k) = xh;
        accM = __builtin_amdgcn_mfma_f32_16x16x32_f16(xh, wh, accM, 0, 0, 0);
        accC = __builtin_amdgcn_mfma_f32_16x16x32_f16(xh, wl, accC, 0, 0, 0);
        accC = __builtin_amdgcn_mfma_f32_16x16x32_f16(xl, wh, accC, 0, 0, 0);
    }
#pragma unroll
    for (int j = 0; j < 4; ++j)
        red[wv][(lane >> 4) * 4 + j][lane & 15] = accM[j] + accC[j] * (1.f/2048.f);
    __syncthreads();
    if (tid < 16) {
        float v1 = -1e30f, v2 = -1e30f; int i1 = 0, i2 = 0;
#pragma unroll
        for (int q = 0; q < NE; ++q) {
            float lv = red[0][tid][q] + red[1][tid][q] + red[2][tid][q] + red[3][tid][q];
            if (lv > v1)      { v2 = v1; i2 = i1; v1 = lv; i1 = q; }
            else if (lv > v2) { v2 = lv; i2 = q; }
        }
        int t = tile0 + tid;
        float e2 = __expf(v2 - v1);
        float inv = 1.f / (1.f + e2);
        tok_e[t] = make_int2(i1, i2);
        tok_w[t] = make_float2(inv, e2 * inv);
        atomicAdd(&hist[i1], 1);
        atomicAdd(&hist[i2], 1);
    }
    __syncthreads();
    if (tid < NE) { int c = hist[tid]; if (c) atomicAdd(&counts[tid], c); }
}

// ---------------- weight fp32->fp16 pre-convert (FULL tier) ----------------
__global__ __launch_bounds__(256) void cvtw_k(const float* __restrict__ Wg,
                                              const float* __restrict__ Wu,
                                              _Float16* __restrict__ Wg16,
                                              _Float16* __restrict__ Wu16) {
    int i = blockIdx.x * 256 + threadIdx.x;        // 524288 float4 per array
    float4 g = reinterpret_cast<const float4*>(Wg)[i];
    float4 u = reinterpret_cast<const float4*>(Wu)[i];
    half4 gh = {(_Float16)g.x,(_Float16)g.y,(_Float16)g.z,(_Float16)g.w};
    half4 uh = {(_Float16)u.x,(_Float16)u.y,(_Float16)u.z,(_Float16)u.w};
    reinterpret_cast<half4*>(Wg16)[i] = gh;
    reinterpret_cast<half4*>(Wu16)[i] = uh;
}

// ---------------- scatter token->slot (with inline padded scan) ----------------
template<bool FULL>
__global__ __launch_bounds__(256) void scatter_k(const int2* __restrict__ tok_e,
                                                 const float2* __restrict__ tok_w,
                                                 const int* __restrict__ counts,
                                                 int* __restrict__ cursors,
                                                 int* __restrict__ slot_tok,
                                                 float* __restrict__ slot_w,
                                                 int2* __restrict__ tok_slots) {
    __shared__ int lcnt[NE];
    __shared__ int lbase[NE];
    __shared__ int offsLds[NE];
    if (threadIdx.x < NE) lcnt[threadIdx.x] = 0;
    if (threadIdx.x == 0) {
        int acc = 0;
#pragma unroll
        for (int e = 0; e < NE; ++e) {
            offsLds[e] = acc;
            acc += ((counts[e] + BMq - 1) / BMq) * BMq;
        }
    }
    __syncthreads();
    int t = blockIdx.x * 256 + threadIdx.x;
    int2 te = tok_e[t]; float2 tw = tok_w[t];
    int p0 = atomicAdd(&lcnt[te.x], 1);
    int p1 = atomicAdd(&lcnt[te.y], 1);
    __syncthreads();
    if (threadIdx.x < NE)
        lbase[threadIdx.x] = atomicAdd(&cursors[threadIdx.x], lcnt[threadIdx.x]);
    __syncthreads();
    int s0 = offsLds[te.x] + lbase[te.x] + p0;
    int s1 = offsLds[te.y] + lbase[te.y] + p1;
    slot_tok[s0] = t; slot_w[s0] = tw.x;
    slot_tok[s1] = t; slot_w[s1] = tw.y;
    if (FULL) tok_slots[t] = make_int2(s0, s1);
}

// ---------------- GEMM1: a = silu(x_gathered @ Wg[e]^T + bg[e]) ----------------
// tile 64 slots x 128 i, BK=128 (8 K-iters). FULL: half staging from x16/Wg16.
template<bool FULL>
__global__ __launch_bounds__(256) void gemm1_k(const float* __restrict__ x,
                                               const _Float16* __restrict__ x16,
                                               const float* __restrict__ Wg,
                                               const _Float16* __restrict__ Wg16,
                                               const float* __restrict__ bg,
                                               const int* __restrict__ counts,
                                               const int* __restrict__ slot_tok,
                                               _Float16* __restrict__ abuf) {
    __shared__ __align__(16) _Float16 As[64 * 128];    // 16KB
    __shared__ __align__(16) _Float16 Bs[128 * 128];   // 32KB
    __shared__ int tokLds[64];
    int row0 = blockIdx.x * BMq;
    int e, total;
    expert_of(counts, row0, e, total);
    if (row0 >= total) return;
    int tid = threadIdx.x;
    if (tid < 64) tokLds[tid] = slot_tok[row0 + tid];
    __syncthreads();
    int wv = tid >> 6, lane = tid & 63;
    f32x4 acc[4][2] = {};
    for (int kk = 0; kk < HDIM; kk += 128) {
        if (FULL) {
            // A: 64 rows x 16 half8 gathered from x16
#pragma unroll
            for (int j = 0; j < 4; ++j) {
                int idx = tid + j * 256;
                int r = idx >> 4, hq = idx & 15;
                int tok = tokLds[r];
                half8 v = {0,0,0,0,0,0,0,0};
                if (tok >= 0) v = *reinterpret_cast<const half8*>(x16 + (size_t)tok * HDIM + kk + hq * 8);
                *reinterpret_cast<half8*>(&As[r * 128 + ((hq * 8) ^ ((r & 7) << 3))]) = v;
            }
            // B: Wg16[e]: 128 rows x 16 half8
#pragma unroll 4
            for (int j = 0; j < 8; ++j) {
                int idx = tid + j * 256;
                int r = idx >> 4, hq = idx & 15;
                half8 v = *reinterpret_cast<const half8*>(Wg16 + (size_t)e * IDIM * HDIM + (size_t)r * HDIM + kk + hq * 8);
                *reinterpret_cast<half8*>(&Bs[r * 128 + ((hq * 8) ^ ((r & 7) << 3))]) = v;
            }
        } else {
            // A: 64 rows x 32 float4 -> fp16
#pragma unroll
            for (int j = 0; j < 8; ++j) {
                int idx = tid + j * 256;
                int r = idx >> 5, kq = idx & 31;
                int tok = tokLds[r];
                float4 v = make_float4(0.f, 0.f, 0.f, 0.f);
                if (tok >= 0) v = *reinterpret_cast<const float4*>(x + (size_t)tok * HDIM + kk + kq * 4);
                half4 hv = {(_Float16)v.x, (_Float16)v.y, (_Float16)v.z, (_Float16)v.w};
                *reinterpret_cast<half4*>(&As[r * 128 + ((kq * 4) ^ ((r & 7) << 3))]) = hv;
            }
            // B: Wg[e] fp32: 128 rows x 32 float4 -> fp16
#pragma unroll 4
            for (int j = 0; j < 16; ++j) {
                int idx = tid + j * 256;
                int r = idx >> 5, kq = idx & 31;
                float4 v = *reinterpret_cast<const float4*>(Wg + (size_t)e * IDIM * HDIM + (size_t)r * HDIM + kk + kq * 4);
                half4 hv = {(_Float16)v.x, (_Float16)v.y, (_Float16)v.z, (_Float16)v.w};
                *reinterpret_cast<half4*>(&Bs[r * 128 + ((kq * 4) ^ ((r & 7) << 3))]) = hv;
            }
        }
        __syncthreads();
#pragma unroll
        for (int ks = 0; ks < 128; ks += 32) {
            int c = ks + ((lane >> 4) << 3);
            half8 af[4], bf[2];
#pragma unroll
            for (int rt = 0; rt < 4; ++rt) {
                int r = rt * 16 + (lane & 15);
                af[rt] = *reinterpret_cast<const half8*>(&As[r * 128 + (c ^ ((r & 7) << 3))]);
            }
#pragma unroll
            for (int ct = 0; ct < 2; ++ct) {
                int r = wv * 32 + ct * 16 + (lane & 15);
                bf[ct] = *reinterpret_cast<const half8*>(&Bs[r * 128 + (c ^ ((r & 7) << 3))]);
            }
#pragma unroll
            for (int rt = 0; rt < 4; ++rt)
#pragma unroll
                for (int ct = 0; ct < 2; ++ct)
                    acc[rt][ct] = __builtin_amdgcn_mfma_f32_16x16x32_f16(af[rt], bf[ct], acc[rt][ct], 0, 0, 0);
        }
        __syncthreads();
    }
#pragma unroll
    for (int rt = 0; rt < 4; ++rt)
#pragma unroll
        for (int ct = 0; ct < 2; ++ct) {
            int i = wv * 32 + ct * 16 + (lane & 15);
            float bgv = bg[e * IDIM + i];
#pragma unroll
            for (int j = 0; j < 4; ++j) {
                int m = rt * 16 + ((lane >> 4) << 2) + j;
                if (tokLds[m] >= 0) {
                    float v = acc[rt][ct][j] + bgv;
                    float sv = v / (1.f + __expf(-v));
                    abuf[(size_t)(row0 + m) * IDIM + i] = (_Float16)sv;
                }
            }
        }
}

// ---------------- GEMM2: O_slot = a @ Wu[e]^T + bu[e] (FULL) / atomic (BASE) ----
template<bool FULL>
__global__ __launch_bounds__(256) void gemm2_k(const _Float16* __restrict__ abuf,
                                               const float* __restrict__ Wu,
                                               const _Float16* __restrict__ Wu16,
                                               const float* __restrict__ bu,
                                               const int* __restrict__ counts,
                                               const int* __restrict__ slot_tok,
                                               const float* __restrict__ slot_w,
                                               float* __restrict__ out,
                                               _Float16* __restrict__ Obuf) {
    __shared__ __align__(16) _Float16 As[64 * 128];
    __shared__ __align__(16) _Float16 Bs[128 * 128];
    __shared__ int   tokLds[64];
    __shared__ float wLds[64];
    int row0 = blockIdx.x * BMq;
    int e, total;
    expert_of(counts, row0, e, total);
    if (row0 >= total) return;
    int h0 = blockIdx.y * 128;
    int tid = threadIdx.x;
    if (tid < 64) { tokLds[tid] = slot_tok[row0 + tid]; wLds[tid] = slot_w[row0 + tid]; }
    // A: abuf rows, 64 x 16 half8
#pragma unroll
    for (int j = 0; j < 4; ++j) {
        int idx = tid + j * 256;
        int r = idx >> 4, hq = idx & 15;
        half8 v = *reinterpret_cast<const half8*>(abuf + (size_t)(row0 + r) * IDIM + hq * 8);
        *reinterpret_cast<half8*>(&As[r * 128 + ((hq * 8) ^ ((r & 7) << 3))]) = v;
    }
    if (FULL) {
        // B: Wu16[e][h0+r][:]: 128 rows x 16 half8
#pragma unroll 4
        for (int j = 0; j < 8; ++j) {
            int idx = tid + j * 256;
            int r = idx >> 4, fq = idx & 15;
            half8 v = *reinterpret_cast<const half8*>(Wu16 + (size_t)e * HDIM * IDIM + (size_t)(h0 + r) * IDIM + fq * 8);
            *reinterpret_cast<half8*>(&Bs[r * 128 + ((fq * 8) ^ ((r & 7) << 3))]) = v;
        }
    } else {
#pragma unroll 4
        for (int j = 0; j < 16; ++j) {
            int idx = tid + j * 256;
            int r = idx >> 5, fq = idx & 31;
            float4 v = *reinterpret_cast<const float4*>(Wu + (size_t)e * HDIM * IDIM + (size_t)(h0 + r) * IDIM + fq * 4);
            half4 hv = {(_Float16)v.x, (_Float16)v.y, (_Float16)v.z, (_Float16)v.w};
            *reinterpret_cast<half4*>(&Bs[r * 128 + ((fq * 4) ^ ((r & 7) << 3))]) = hv;
        }
    }
    __syncthreads();
    int wv = tid >> 6, lane = tid & 63;
    f32x4 acc[4][2] = {};
#pragma unroll
    for (int ks = 0; ks < 128; ks += 32) {
        int c = ks + ((lane >> 4) << 3);
        half8 af[4], bf[2];
#pragma unroll
        for (int rt = 0; rt < 4; ++rt) {
            int r = rt * 16 + (lane & 15);
            af[rt] = *reinterpret_cast<const half8*>(&As[r * 128 + (c ^ ((r & 7) << 3))]);
        }
#pragma unroll
        for (int ct = 0; ct < 2; ++ct) {
            int r = wv * 32 + ct * 16 + (lane & 15);
            bf[ct] = *reinterpret_cast<const half8*>(&Bs[r * 128 + (c ^ ((r & 7) << 3))]);
        }
#pragma unroll
        for (int rt = 0; rt < 4; ++rt)
#pragma unroll
            for (int ct = 0; ct < 2; ++ct)
                acc[rt][ct] = __builtin_amdgcn_mfma_f32_16x16x32_f16(af[rt], bf[ct], acc[rt][ct], 0, 0, 0);
    }
#pragma unroll
    for (int rt = 0; rt < 4; ++rt)
#pragma unroll
        for (int ct = 0; ct < 2; ++ct) {
            int h = h0 + wv * 32 + ct * 16 + (lane & 15);
            float buv = bu[e * HDIM + h];
#pragma unroll
            for (int j = 0; j < 4; ++j) {
                int m = rt * 16 + ((lane >> 4) << 2) + j;
                if (FULL) {
                    Obuf[(size_t)(row0 + m) * HDIM + h] = (_Float16)(acc[rt][ct][j] + buv);
                } else {
                    int tok = tokLds[m];
                    if (tok >= 0)
                        atomicAdd(out + (size_t)tok * HDIM + h,
                                  (acc[rt][ct][j] + buv) * wLds[m]);
                }
            }
        }
}

// ---------------- combine (FULL): out[t] = w1*O1 + w2*O2 ----------------
__global__ __launch_bounds__(256) void combine_k(const _Float16* __restrict__ Obuf,
                                                 const int2* __restrict__ tok_slots,
                                                 const float2* __restrict__ tok_w,
                                                 float* __restrict__ out) {
    int wv = threadIdx.x >> 6, lane = threadIdx.x & 63;
    int t = blockIdx.x * 4 + wv;
    int2   sl = tok_slots[t];
    float2 tw = tok_w[t];
    const _Float16* O1 = Obuf + (size_t)sl.x * HDIM;
    const _Float16* O2 = Obuf + (size_t)sl.y * HDIM;
    float* op = out + (size_t)t * HDIM;
#pragma unroll
    for (int q = 0; q < 4; ++q) {
        int h = q * 256 + lane * 4;
        half4  a1 = *reinterpret_cast<const half4*>(O1 + h);
        half4  a2 = *reinterpret_cast<const half4*>(O2 + h);
        float4 o;
        o.x = tw.x * (float)a1[0] + tw.y * (float)a2[0];
        o.y = tw.x * (float)a1[1] + tw.y * (float)a2[1];
        o.z = tw.x * (float)a1[2] + tw.y * (float)a2[2];
        o.w = tw.x * (float)a1[3] + tw.y * (float)a2[3];
        *reinterpret_cast<float4*>(op + h) = o;
    }
}

extern "C" void kernel_launch(void* const* d_in, const int* in_sizes, int n_in,
                              void* d_out, int out_size, void* d_ws, size_t ws_size,
                              hipStream_t stream) {
    const float* x  = (const float*)d_in[0];
    const float* Wr = (const float*)d_in[1];
    const float* Wg = (const float*)d_in[2];
    const float* bg = (const float*)d_in[3];
    const float* Wu = (const float*)d_in[4];
    const float* bu = (const float*)d_in[5];
    float* out = (float*)d_out;
    char* ws = (char*)d_ws;

    int2*      tok_e    = (int2*)(ws + WS_TOKE);
    float2*    tok_w    = (float2*)(ws + WS_TOKW);
    int*       counts   = (int*)(ws + WS_CNT);
    int*       cursors  = (int*)(ws + WS_CUR);
    int*       slot_tok = (int*)(ws + WS_STOK);
    float*     slot_w   = (float*)(ws + WS_SW);
    _Float16*  abuf     = (_Float16*)(ws + WS_ABUF);
    int2*      tok_slots= (int2*)(ws + WS_TSLOT);
    _Float16*  Wg16     = (_Float16*)(ws + WS_WG16);
    _Float16*  Wu16     = (_Float16*)(ws + WS_WU16);
    _Float16*  x16      = (_Float16*)(ws + WS_X16);
    _Float16*  Obuf     = (_Float16*)(ws + WS_OBUF);

    const bool full = (ws_size >= WS_FULL_END);   // constant per process -> capture-safe

    hipMemsetAsync(ws + WS_CNT, 0, 256, stream);  // counts+cursors

    if (full) {
        cvtw_k   <<<2048, 256, 0, stream>>>(Wg, Wu, Wg16, Wu16);
        router_k<true><<<T_TOK/16, 256, 0, stream>>>(x, Wr, tok_e, tok_w, x16, counts, slot_tok);
        scatter_k<true><<<T_TOK/256, 256, 0, stream>>>(tok_e, tok_w, counts, cursors, slot_tok, slot_w, tok_slots);
        gemm1_k<true><<<NBLK1, 256, 0, stream>>>(x, x16, Wg, Wg16, bg, counts, slot_tok, abuf);
        dim3 g2(NBLK1, 8);
        gemm2_k<true><<<g2, 256, 0, stream>>>(abuf, Wu, Wu16, bu, counts, slot_tok, slot_w, out, Obuf);
        combine_k<<<T_TOK/4, 256, 0, stream>>>(Obuf, tok_slots, tok_w, out);
    } else {
        hipMemsetAsync(d_out, 0, (size_t)T_TOK * HDIM * sizeof(float), stream);
        router_k<false><<<T_TOK/16, 256, 0, stream>>>(x, Wr, tok_e, tok_w, nullptr, counts, slot_tok);
        scatter_k<false><<<T_TOK/256, 256, 0, stream>>>(tok_e, tok_w, counts, cursors, slot_tok, slot_w, nullptr);
        gemm1_k<false><<<NBLK1, 256, 0, stream>>>(x, nullptr, Wg, nullptr, bg, counts, slot_tok, abuf);
        dim3 g2(NBLK1, 8);
        gemm2_k<false><<<g2, 256, 0, stream>>>(abuf, Wu, nullptr, bu, counts, slot_tok, slot_w, out, nullptr);
    }
}